// Round 8
// baseline (263.766 us; speedup 1.0000x reference)
//
#include <hip/hip_runtime.h>
#include <cstddef>

#define B   2
#define S   1024
#define PP  1024          // start_pos
#define CTX 2048
#define E   2048
#define H   32
#define KVH 8
#define HD  64
#define GQ  4             // H / KVH
#define NQKV 3072         // E + 2*KVH*HD

typedef short s4v  __attribute__((ext_vector_type(4)));
typedef short s8v  __attribute__((ext_vector_type(8)));
typedef float f4v  __attribute__((ext_vector_type(4)));

__device__ __forceinline__ short f2bf(float f) {   // RNE f32 -> bf16
  union { float f; unsigned u; } v; v.f = f;
  unsigned r = v.u + 0x7fffu + ((v.u >> 16) & 1u);
  return (short)(r >> 16);
}
__device__ __forceinline__ float bf2f(short h) {
  union { unsigned u; float f; } v; v.u = ((unsigned)(unsigned short)h) << 16;
  return v.f;
}

__device__ __forceinline__ void gl_lds16(const void* g, void* l) {
  // async 16B/lane global->LDS; LDS dest = wave-uniform base + lane*16
  __builtin_amdgcn_global_load_lds((const __attribute__((address_space(1))) unsigned*)g,
                                   (__attribute__((address_space(3))) unsigned*)l, 16, 0, 0);
}

// ---------------------------------------------------------------------------
// prep: only the sections qkv_gemm DEPENDS on (x + Wq/Wk/Wv converts).
// [0,2048) x | [2048,4096) Wq | [4096,4608) Wk | [4608,5120) Wv
// ---------------------------------------------------------------------------
__global__ __launch_bounds__(256) void prep(const float* __restrict__ x,
                                            const float* __restrict__ Wq,
                                            const float* __restrict__ Wk,
                                            const float* __restrict__ Wv,
                                            short* __restrict__ xb,
                                            short* __restrict__ wqkv) {
  const int blk = blockIdx.x, tid = threadIdx.x;
  const float* s; short* d; int base;
  if (blk < 2048)      { s = x;  d = xb;             base = blk; }
  else if (blk < 4096) { s = Wq; d = wqkv;           base = blk - 2048; }
  else if (blk < 4608) { s = Wk; d = wqkv + 4194304; base = blk - 4096; }
  else                 { s = Wv; d = wqkv + 5242880; base = blk - 4608; }
  int i = (base * 256 + tid) * 8;
  float4 a = *(const float4*)&s[i];
  float4 b = *(const float4*)&s[i + 4];
  s8v o;
  o[0]=f2bf(a.x); o[1]=f2bf(a.y); o[2]=f2bf(a.z); o[3]=f2bf(a.w);
  o[4]=f2bf(b.x); o[5]=f2bf(b.y); o[6]=f2bf(b.z); o[7]=f2bf(b.w);
  *(s8v*)&d[i] = o;
}

// ---------------------------------------------------------------------------
// QKV GEMM (ids [0,384)) + aux prep blocks (ids [384,3200)).
// GEMM: BK=64, 2-phase dbuf staging, fused epilogue (q bf16; K RoPE'd
// in-register -> keys; V -> permuted valsT).
// Aux: [0,2048) Wo convert | [2048,2560) cache_k | [2560,2816) vT_old.
// (out zeroing moved to hipMemsetAsync in the launcher.)
// ---------------------------------------------------------------------------
__global__ __launch_bounds__(256) void qkv_gemm(const short* __restrict__ A,
                                                const short* __restrict__ Bw,
                                                const float* __restrict__ cosb,
                                                const float* __restrict__ sinb,
                                                const float* __restrict__ Wo,
                                                const float* __restrict__ ck,
                                                const float* __restrict__ cv,
                                                short* __restrict__ qb,
                                                short* __restrict__ keys,
                                                short* __restrict__ vt,
                                                short* __restrict__ wob) {
  __shared__ short As[2][8192];
  __shared__ short Bs[2][8192];
  const int tid = threadIdx.x;
  const int id  = blockIdx.x;

  if (id >= 384) {                     // ---------- aux prep blocks ----------
    const int aux = id - 384;
    if (aux < 2048) {
      // Wo f32 -> bf16
      int i = (aux * 256 + tid) * 8;
      float4 a = *(const float4*)&Wo[i];
      float4 b = *(const float4*)&Wo[i + 4];
      s8v o;
      o[0]=f2bf(a.x); o[1]=f2bf(a.y); o[2]=f2bf(a.z); o[3]=f2bf(a.w);
      o[4]=f2bf(b.x); o[5]=f2bf(b.y); o[6]=f2bf(b.z); o[7]=f2bf(b.w);
      *(s8v*)&wob[i] = o;
    } else if (aux < 2560) {
      // cache_k f32 [0,PP) -> bf16 keys
      int idx = (aux - 2048) * 256 + tid;
      int bkv = idx >> 13;
      int rem = idx & 8191;
      size_t off = (size_t)bkv * (CTX * HD) + (size_t)rem * 8;
      float4 a = *(const float4*)&ck[off];
      float4 b = *(const float4*)&ck[off + 4];
      s8v o;
      o[0]=f2bf(a.x); o[1]=f2bf(a.y); o[2]=f2bf(a.z); o[3]=f2bf(a.w);
      o[4]=f2bf(b.x); o[5]=f2bf(b.y); o[6]=f2bf(b.z); o[7]=f2bf(b.w);
      *(s8v*)&keys[off] = o;
    } else {
      // cache_v [0,PP) -> valsT (permuted key order within 64-blocks)
      short (*Ts)[72] = (short (*)[72])&As[0][0];   // reuse GEMM LDS
      const int blk2 = aux - 2560;              // B*KVH*(PP/64) = 256
      const int bkv = blk2 >> 4;
      const int p0  = (blk2 & 15) * 64;
      const float* src = cv + (size_t)bkv * CTX * HD + (size_t)p0 * HD;
      {
        int dq = tid & 15, kb = tid >> 4;
        float4 vv[4];
#pragma unroll
        for (int i = 0; i < 4; i++)
          vv[i] = *(const float4*)&src[(size_t)(kb * 4 + i) * HD + dq * 4];
#pragma unroll
        for (int j = 0; j < 4; j++) {
          s4v p;
          p[0]=f2bf(((const float*)&vv[0])[j]); p[1]=f2bf(((const float*)&vv[1])[j]);
          p[2]=f2bf(((const float*)&vv[2])[j]); p[3]=f2bf(((const float*)&vv[3])[j]);
          *(s4v*)&Ts[dq * 4 + j][kb * 4] = p;
        }
      }
      __syncthreads();
      {
        int d = tid >> 2, c = tid & 3;
        short* dst = vt + ((size_t)bkv * HD + d) * CTX + p0 + (c >> 1) * 32 + (c & 1) * 4;
#pragma unroll
        for (int j = 0; j < 4; j++) {
          s4v q4 = *(const s4v*)&Ts[d][c * 16 + j * 4];
          *(s4v*)&dst[j * 8] = q4;
        }
      }
    }
    return;
  }

  // ------------------------------ GEMM blocks ------------------------------
  const int wv   = tid >> 6, lane = tid & 63;
  const int wm   = wv & 1, wn = wv >> 1;
  const int n16  = lane & 15, g = lane >> 4;
  const int m0   = (id / 24) * 128, n0 = (id % 24) * 128;
  const int K = 2048;

  const int rr = tid >> 3;                          // 0..31 rows per stage step
  const int cc = ((tid & 7) ^ (rr & 7)) * 8;        // pre-swizzled col chunk
  const short* pA = A  + (size_t)(m0 + rr) * K + cc;
  const short* pB = Bw + (size_t)(n0 + rr) * K + cc;

  auto stage = [&](int buf, int kofs) {
#pragma unroll
    for (int st = 0; st < 4; st++) {
      gl_lds16(pA + kofs + (size_t)st * 32 * K, &As[buf][(st * 256 + wv * 64) * 8]);
      gl_lds16(pB + kofs + (size_t)st * 32 * K, &Bs[buf][(st * 256 + wv * 64) * 8]);
    }
  };

  f4v acc[4][4] = {};
  stage(0, 0);
  int cur = 0;
  for (int k0 = 0; k0 < K; k0 += 64) {
    __syncthreads();                       // buf[cur] ready (drain after compute)
    if (k0 + 64 < K) stage(cur ^ 1, k0 + 64);

#pragma unroll
    for (int kk = 0; kk < 2; kk++) {
      s8v af[4], bf[4];
#pragma unroll
      for (int mt = 0; mt < 4; mt++)
        af[mt] = *(const s8v*)&As[cur][(wm * 64 + mt * 16 + n16) * 64 + (((kk << 2) | g) ^ (n16 & 7)) * 8];
#pragma unroll
      for (int nt = 0; nt < 4; nt++)
        bf[nt] = *(const s8v*)&Bs[cur][(wn * 64 + nt * 16 + n16) * 64 + (((kk << 2) | g) ^ (n16 & 7)) * 8];
#pragma unroll
      for (int mt = 0; mt < 4; mt++)
#pragma unroll
        for (int nt = 0; nt < 4; nt++)
          acc[mt][nt] = __builtin_amdgcn_mfma_f32_16x16x32_bf16(af[mt], bf[nt], acc[mt][nt], 0, 0, 0);
    }
    cur ^= 1;
  }

  const int rowb = m0 + wm * 64 + g * 4;
  const int colb = n0 + wn * 64 + n16;
  if (n0 < 2048) {
    // Q region -> qb (B,S,E) bf16
#pragma unroll
    for (int mt = 0; mt < 4; mt++)
#pragma unroll
      for (int nt = 0; nt < 4; nt++) {
        size_t base = (size_t)(rowb + mt * 16) * E + colb + nt * 16;
#pragma unroll
        for (int r = 0; r < 4; r++)
          qb[base + (size_t)r * E] = f2bf(acc[mt][nt][r]);
      }
  } else if (n0 < 2560) {
    // K region: RoPE in-register (f32), scatter into keys at pos PP+s.
    const int kvh = ((n0 - 2048) >> 6) + wn;
#pragma unroll
    for (int mt = 0; mt < 4; mt++) {
      const int row = rowb + mt * 16;          // in [0, B*S)
      const int bb = row >> 10, s = row & 1023;
      const float* crow = cosb + ((size_t)bb * S + s) * HD;
      const float* srow = sinb + ((size_t)bb * S + s) * HD;
      const size_t kdst = (((size_t)bb * KVH + kvh) * CTX + PP + s) * HD;
#pragma unroll
      for (int nt = 0; nt < 2; nt++) {
        const int d = n16 + nt * 16;
#pragma unroll
        for (int r = 0; r < 4; r++) {
          float c  = crow[r * HD + d];
          float sn = srow[r * HD + d];
          float k1 = acc[mt][nt][r], k2 = acc[mt][nt + 2][r];
          keys[kdst + (size_t)r * HD + d]      = f2bf(k1 * c - k2 * sn);
          keys[kdst + (size_t)r * HD + d + 32] = f2bf(k2 * c + k1 * sn);
        }
      }
    }
  } else {
    // V region -> valsT[(bkv*HD+d)*CTX + PP + perm(s)]
    const int b    = m0 >> 10;
    const int head = ((n0 - 2560) >> 6) + wn;
    const int sbase = (m0 - (b << 10)) + wm * 64;   // multiple of 64
    const size_t vrowb = (size_t)(b * KVH + head) * HD;
#pragma unroll
    for (int mt = 0; mt < 4; mt++) {
      const int pos = PP + sbase + ((mt >> 1) << 5) + ((mt & 1) << 2) + (g << 3);
#pragma unroll
      for (int nt = 0; nt < 4; nt++) {
        const int d = nt * 16 + n16;
        s4v o;
        o[0] = f2bf(acc[mt][nt][0]); o[1] = f2bf(acc[mt][nt][1]);
        o[2] = f2bf(acc[mt][nt][2]); o[3] = f2bf(acc[mt][nt][3]);
        *(s4v*)&vt[(vrowb + d) * CTX + pos] = o;
      }
    }
  }
}

// ---------------------------------------------------------------------------
// bf16 MFMA GEMM, BK=64, 2-phase double-buffered staging, split-K=2,
// atomic f32 accumulate (for O-proj).
// ---------------------------------------------------------------------------
__global__ __launch_bounds__(256) void gemm_bf16_sk(const short* __restrict__ A,
                                                    const short* __restrict__ Bw,
                                                    float* __restrict__ C,
                                                    int M, int N, int K) {
  __shared__ short As[2][8192];
  __shared__ short Bs[2][8192];
  const int tid  = threadIdx.x;
  const int wv   = tid >> 6, lane = tid & 63;
  const int wm   = wv & 1, wn = wv >> 1;
  const int n16  = lane & 15, g = lane >> 4;
  const int m0   = blockIdx.y * 128, n0 = blockIdx.x * 128;
  const int kh   = K >> 1;
  const int kbeg = blockIdx.z * kh;

  const int rr = tid >> 3;
  const int cc = ((tid & 7) ^ (rr & 7)) * 8;
  const short* pA = A  + (size_t)(m0 + rr) * K + kbeg + cc;
  const short* pB = Bw + (size_t)(n0 + rr) * K + kbeg + cc;

  auto stage = [&](int buf, int kofs) {
#pragma unroll
    for (int st = 0; st < 4; st++) {
      gl_lds16(pA + kofs + (size_t)st * 32 * K, &As[buf][(st * 256 + wv * 64) * 8]);
      gl_lds16(pB + kofs + (size_t)st * 32 * K, &Bs[buf][(st * 256 + wv * 64) * 8]);
    }
  };

  f4v acc[4][4] = {};
  stage(0, 0);
  int cur = 0;
  for (int k0 = 0; k0 < kh; k0 += 64) {
    __syncthreads();
    if (k0 + 64 < kh) stage(cur ^ 1, k0 + 64);

#pragma unroll
    for (int kk = 0; kk < 2; kk++) {
      s8v af[4], bf[4];
#pragma unroll
      for (int mt = 0; mt < 4; mt++)
        af[mt] = *(const s8v*)&As[cur][(wm * 64 + mt * 16 + n16) * 64 + (((kk << 2) | g) ^ (n16 & 7)) * 8];
#pragma unroll
      for (int nt = 0; nt < 4; nt++)
        bf[nt] = *(const s8v*)&Bs[cur][(wn * 64 + nt * 16 + n16) * 64 + (((kk << 2) | g) ^ (n16 & 7)) * 8];
#pragma unroll
      for (int mt = 0; mt < 4; mt++)
#pragma unroll
        for (int nt = 0; nt < 4; nt++)
          acc[mt][nt] = __builtin_amdgcn_mfma_f32_16x16x32_bf16(af[mt], bf[nt], acc[mt][nt], 0, 0, 0);
    }
    cur ^= 1;
  }

#pragma unroll
  for (int mt = 0; mt < 4; mt++)
#pragma unroll
    for (int nt = 0; nt < 4; nt++) {
      size_t base = (size_t)(m0 + wm * 64 + mt * 16 + g * 4) * N + n0 + wn * 64 + nt * 16 + n16;
#pragma unroll
      for (int r = 0; r < 4; r++)
        unsafeAtomicAdd(&C[base + (size_t)r * N], acc[mt][nt][r]);
    }
}

// ---------------------------------------------------------------------------
// MFMA flash attention v4: 2 waves/block (128 thr), 32 q-rows per wave.
// K/V fragment LDS reads are q-independent, so one set of 16 ds_read_b128
// per tile now feeds 32 MFMA (2x FLOP per LDS byte vs R1's 16 q-rows).
// Same 1024 blocks, same 16KB LDS, same verified chunk-XOR swizzle
// (0-conflict), same 2-barrier staging. exp2 softmax, no max-bias,
// cvt_pk packing, parallel l-chains, setprio on MFMA clusters.
// ---------------------------------------------------------------------------
__global__ __launch_bounds__(128) void attn_mfma(const short* __restrict__ qb,
                                                 const float* __restrict__ cosb,
                                                 const float* __restrict__ sinb,
                                                 const short* __restrict__ keys,
                                                 const short* __restrict__ valsT,
                                                 short* __restrict__ attn) {
  __shared__ short Ks[4096];    // K tile [key][dim] 64x64, chunk-swizzled
  __shared__ short VTs[4096];   // V^T tile [dim][permuted key], chunk-swizzled

  const int sblk = 15 - (blockIdx.x & 15);     // long blocks first
  const int h    = (blockIdx.x >> 4) & (H - 1);
  const int b    = blockIdx.x >> 9;
  const int kv   = h >> 2;
  const int sq0  = sblk * 64;
  const int kend = PP + sq0 + 64;

  const int tid  = threadIdx.x;
  const int w    = tid >> 6;                   // 0..1
  const int lane = tid & 63;
  const int n    = lane & 15;
  const int g    = lane >> 4;

  const short* kbase = keys  + ((size_t)b * KVH + kv) * CTX * HD;
  const short* vtb   = valsT + ((size_t)b * KVH + kv) * (size_t)HD * CTX;

  // ---- Q frags for the wave's 2 q-groups: RoPE fused, scale=0.125*log2e --
  s8v qlo[2], qhi[2];
#pragma unroll
  for (int qg = 0; qg < 2; qg++) {
    const size_t row = (size_t)b * S + sq0 + w * 32 + qg * 16 + n;
    const short* qrow = qb + row * E + h * 64;
    const float* crow = cosb + row * HD;
    const float* srow = sinb + row * HD;
    const float SC = 0.18033688011112042f;   // 0.125 * log2(e)
    s8v q0 = *(const s8v*)&qrow[g * 8];
    s8v q1 = *(const s8v*)&qrow[32 + g * 8];
    float cc[8], ss[8];
    *(float4*)&cc[0] = *(const float4*)&crow[g * 8];
    *(float4*)&cc[4] = *(const float4*)&crow[g * 8 + 4];
    *(float4*)&ss[0] = *(const float4*)&srow[g * 8];
    *(float4*)&ss[4] = *(const float4*)&srow[g * 8 + 4];
#pragma unroll
    for (int j = 0; j < 8; j++) {
      float fl = bf2f(q0[j]), fh = bf2f(q1[j]);
      qlo[qg][j] = f2bf((fl * cc[j] - fh * ss[j]) * SC);
      qhi[qg][j] = f2bf((fh * cc[j] + fl * ss[j]) * SC);
    }
  }

  f4v O[2][4] = {};
  float la[2][4] = {};
  const int qmin_w = PP + sq0 + w * 32;        // wave's min query position

  // gl_lds staging: wave w stages rows [w*32, w*32+32) of each 64x64 tile
  // via 4 calls of 8 rows; lane: row = w*32 + j*8 + (lane>>3), chunk slot
  // lane&7 holds global chunk (lane&7)^(row&7) — same swizzle as R1.
  const int lrow = lane >> 3;
  const int sw   = (lane & 7) ^ lrow;
  const short* kg = kbase + (size_t)(w * 32 + lrow) * HD + sw * 8;
  const short* vg = vtb + (size_t)(w * 32 + lrow) * CTX + sw * 8;
  short* const kl = Ks  + (w * 32) * 64;
  short* const vl = VTs + (w * 32) * 64;

  const int xsl = (g ^ (n & 7)) * 8;   // swizzled frag slot (lo); hi = ^32

  for (int k0 = 0; k0 < kend; k0 += 64) {
    __syncthreads();
#pragma unroll
    for (int j = 0; j < 4; j++) {
      gl_lds16(kg + (size_t)(k0 + j * 8) * HD, kl + j * 512);
      gl_lds16(vg + (size_t)(j * 8) * CTX + k0, vl + j * 512);
    }
    __syncthreads();

    if (k0 >= qmin_w + 32) continue;   // wave's K-range done (barriers aligned)

    // ---- S^T = K_tile @ Q^T; K frags shared across both q-groups ----
    f4v sc[2][4];
    __builtin_amdgcn_s_setprio(1);
#pragma unroll
    for (int st = 0; st < 4; st++) {
      const short* krow = &Ks[(st * 16 + n) * 64];
      s8v alo = *(const s8v*)(krow + xsl);
      s8v ahi = *(const s8v*)(krow + (xsl ^ 32));
#pragma unroll
      for (int qg = 0; qg < 2; qg++) {
        f4v z = {0.f, 0.f, 0.f, 0.f};
        z = __builtin_amdgcn_mfma_f32_16x16x32_bf16(alo, qlo[qg], z, 0, 0, 0);
        sc[qg][st] = __builtin_amdgcn_mfma_f32_16x16x32_bf16(ahi, qhi[qg], z, 0, 0, 0);
      }
    }
    __builtin_amdgcn_s_setprio(0);

    // ---- causal mask near diagonal ----
    if (k0 + 63 > qmin_w) {
#pragma unroll
      for (int qg = 0; qg < 2; qg++) {
        const int qp = qmin_w + qg * 16 + n;
#pragma unroll
        for (int st = 0; st < 4; st++)
#pragma unroll
          for (int r = 0; r < 4; r++) {
            int kpos = k0 + st * 16 + g * 4 + r;
            if (kpos > qp) sc[qg][st][r] = -3e38f;
          }
      }
    }

    // ---- exp2 softmax; P^T packed into PV B-operand regs via cvt_pk ----
    union pu { unsigned u[4]; s8v v; } pb0[2], pb1[2];
#pragma unroll
    for (int qg = 0; qg < 2; qg++) {
#pragma unroll
      for (int st = 0; st < 4; st++) {
        float e0 = __builtin_amdgcn_exp2f(sc[qg][st][0]);
        float e1 = __builtin_amdgcn_exp2f(sc[qg][st][1]);
        float e2 = __builtin_amdgcn_exp2f(sc[qg][st][2]);
        float e3 = __builtin_amdgcn_exp2f(sc[qg][st][3]);
        la[qg][0] += e0; la[qg][1] += e1; la[qg][2] += e2; la[qg][3] += e3;
        unsigned w0, w1;
        asm("v_cvt_pk_bf16_f32 %0, %1, %2" : "=v"(w0) : "v"(e0), "v"(e1));
        asm("v_cvt_pk_bf16_f32 %0, %1, %2" : "=v"(w1) : "v"(e2), "v"(e3));
        if (st < 2) { pb0[qg].u[st * 2] = w0; pb0[qg].u[st * 2 + 1] = w1; }
        else        { pb1[qg].u[(st - 2) * 2] = w0; pb1[qg].u[(st - 2) * 2 + 1] = w1; }
      }
    }

    // ---- O^T += V^T @ P; V frags shared across both q-groups ----
    __builtin_amdgcn_s_setprio(1);
#pragma unroll
    for (int dg = 0; dg < 4; dg++) {
      const short* vr = &VTs[(dg * 16 + n) * 64];
      s8v va = *(const s8v*)(vr + xsl);
      s8v vx = *(const s8v*)(vr + (xsl ^ 32));
#pragma unroll
      for (int qg = 0; qg < 2; qg++) {
        O[qg][dg] = __builtin_amdgcn_mfma_f32_16x16x32_bf16(va, pb0[qg].v, O[qg][dg], 0, 0, 0);
        O[qg][dg] = __builtin_amdgcn_mfma_f32_16x16x32_bf16(vx, pb1[qg].v, O[qg][dg], 0, 0, 0);
      }
    }
    __builtin_amdgcn_s_setprio(0);
  }

  // ---- per-qg: reduce l across 4 g-lanes, normalize, store ----
#pragma unroll
  for (int qg = 0; qg < 2; qg++) {
    float l = (la[qg][0] + la[qg][1]) + (la[qg][2] + la[qg][3]);
    l += __shfl_xor(l, 16);
    l += __shfl_xor(l, 32);
    const float rl = 1.f / l;
    short* orow = attn + ((size_t)b * S + sq0 + w * 32 + qg * 16 + n) * E + h * 64;
#pragma unroll
    for (int dg = 0; dg < 4; dg++) {
      s4v o;
      o[0] = f2bf(O[qg][dg][0] * rl); o[1] = f2bf(O[qg][dg][1] * rl);
      o[2] = f2bf(O[qg][dg][2] * rl); o[3] = f2bf(O[qg][dg][3] * rl);
      *(s4v*)&orow[dg * 16 + g * 4] = o;
    }
  }
}

// ---------------------------------------------------------------------------
extern "C" void kernel_launch(void* const* d_in, const int* in_sizes, int n_in,
                              void* d_out, int out_size, void* d_ws, size_t ws_size,
                              hipStream_t stream) {
  const float* x       = (const float*)d_in[0];
  const float* cosb    = (const float*)d_in[1];
  const float* sinb    = (const float*)d_in[2];
  const float* cache_k = (const float*)d_in[4];
  const float* cache_v = (const float*)d_in[5];
  const float* Wq      = (const float*)d_in[6];
  const float* Wk      = (const float*)d_in[7];
  const float* Wv      = (const float*)d_in[8];
  const float* Wo      = (const float*)d_in[9];
  float* out = (float*)d_out;

  short* xb    = (short*)d_ws;                 // 4,194,304
  short* wqkv  = xb + 4194304;                 // 6,291,456
  short* wob   = wqkv + 6291456;               // 4,194,304
  short* keysb = wob + 4194304;                // 2,097,152
  short* valsT = keysb + 2097152;              // 2,097,152 (permuted V^T)
  short* aout  = valsT + 2097152;              // 4,194,304
  short* qb    = aout + 4194304;               // 4,194,304  (~55 MB total)

  dim3 blk(256);

  // 0) zero f32 out for O-proj split-K atomics (stream-ordered, capturable)
  hipMemsetAsync(out, 0, (size_t)out_size, stream);

  // 1) converts qkv_gemm depends on (x, Wq, Wk, Wv)
  prep<<<5120, blk, 0, stream>>>(x, Wq, Wk, Wv, xb, wqkv);

  // 2) fused QKV projection (384 GEMM blocks) + aux prep (2816 blocks:
  //    Wo convert, cache_k, vT_old) filling idle CUs
  qkv_gemm<<<3200, blk, 0, stream>>>(xb, wqkv, cosb, sinb, Wo, cache_k, cache_v,
                                     qb, keysb, valsT, wob);

  // 3) attention v4 (2 waves/block, 32 q-rows/wave) -> bf16 (B,S,E)
  attn_mfma<<<B * H * (S / 64), dim3(128), 0, stream>>>(qb, cosb, sinb, keysb, valsT, aout);

  // 4) output projection, split-K=2 -> f32 out
  gemm_bf16_sk<<<dim3(E / 128, (B * S) / 128, 2), blk, 0, stream>>>(aout, wob, out, B * S, E, E);
}

// Round 9
// 255.596 us; speedup vs baseline: 1.0320x; 1.0320x over previous
//
#include <hip/hip_runtime.h>
#include <cstddef>

#define B   2
#define S   1024
#define PP  1024          // start_pos
#define CTX 2048
#define E   2048
#define H   32
#define KVH 8
#define HD  64
#define GQ  4             // H / KVH
#define NQKV 3072         // E + 2*KVH*HD

typedef short s4v  __attribute__((ext_vector_type(4)));
typedef short s8v  __attribute__((ext_vector_type(8)));
typedef float f4v  __attribute__((ext_vector_type(4)));

__device__ __forceinline__ short f2bf(float f) {   // RNE f32 -> bf16
  union { float f; unsigned u; } v; v.f = f;
  unsigned r = v.u + 0x7fffu + ((v.u >> 16) & 1u);
  return (short)(r >> 16);
}
__device__ __forceinline__ float bf2f(short h) {
  union { unsigned u; float f; } v; v.u = ((unsigned)(unsigned short)h) << 16;
  return v.f;
}

__device__ __forceinline__ void gl_lds16(const void* g, void* l) {
  // async 16B/lane global->LDS; LDS dest = wave-uniform base + lane*16
  __builtin_amdgcn_global_load_lds((const __attribute__((address_space(1))) unsigned*)g,
                                   (__attribute__((address_space(3))) unsigned*)l, 16, 0, 0);
}

// ---------------------------------------------------------------------------
// prep: only the sections qkv_gemm DEPENDS on (x + Wq/Wk/Wv converts).
// [0,2048) x | [2048,4096) Wq | [4096,4608) Wk | [4608,5120) Wv
// ---------------------------------------------------------------------------
__global__ __launch_bounds__(256) void prep(const float* __restrict__ x,
                                            const float* __restrict__ Wq,
                                            const float* __restrict__ Wk,
                                            const float* __restrict__ Wv,
                                            short* __restrict__ xb,
                                            short* __restrict__ wqkv) {
  const int blk = blockIdx.x, tid = threadIdx.x;
  const float* s; short* d; int base;
  if (blk < 2048)      { s = x;  d = xb;             base = blk; }
  else if (blk < 4096) { s = Wq; d = wqkv;           base = blk - 2048; }
  else if (blk < 4608) { s = Wk; d = wqkv + 4194304; base = blk - 4096; }
  else                 { s = Wv; d = wqkv + 5242880; base = blk - 4608; }
  int i = (base * 256 + tid) * 8;
  float4 a = *(const float4*)&s[i];
  float4 b = *(const float4*)&s[i + 4];
  s8v o;
  o[0]=f2bf(a.x); o[1]=f2bf(a.y); o[2]=f2bf(a.z); o[3]=f2bf(a.w);
  o[4]=f2bf(b.x); o[5]=f2bf(b.y); o[6]=f2bf(b.z); o[7]=f2bf(b.w);
  *(s8v*)&d[i] = o;
}

// ---------------------------------------------------------------------------
// QKV GEMM (ids [0,384)) + aux prep blocks (ids [384,3200)).
// GEMM: BK=64, 2-phase dbuf staging, fused epilogue (q bf16; K RoPE'd
// in-register -> keys; V -> permuted valsT). GEMM tile ids are XCD-chunk
// swizzled (bijective, nwg=384=8*48): XCD x owns M-bands 2x..2x+1 so each
// A-panel is fetched into ONE XCD L2 instead of all eight (T1).
// Aux: [0,2048) Wo convert | [2048,2560) cache_k | [2560,2816) vT_old.
// ---------------------------------------------------------------------------
__global__ __launch_bounds__(256) void qkv_gemm(const short* __restrict__ A,
                                                const short* __restrict__ Bw,
                                                const float* __restrict__ cosb,
                                                const float* __restrict__ sinb,
                                                const float* __restrict__ Wo,
                                                const float* __restrict__ ck,
                                                const float* __restrict__ cv,
                                                short* __restrict__ qb,
                                                short* __restrict__ keys,
                                                short* __restrict__ vt,
                                                short* __restrict__ wob) {
  __shared__ short As[2][8192];
  __shared__ short Bs[2][8192];
  const int tid = threadIdx.x;
  const int id  = blockIdx.x;

  if (id >= 384) {                     // ---------- aux prep blocks ----------
    const int aux = id - 384;
    if (aux < 2048) {
      // Wo f32 -> bf16
      int i = (aux * 256 + tid) * 8;
      float4 a = *(const float4*)&Wo[i];
      float4 b = *(const float4*)&Wo[i + 4];
      s8v o;
      o[0]=f2bf(a.x); o[1]=f2bf(a.y); o[2]=f2bf(a.z); o[3]=f2bf(a.w);
      o[4]=f2bf(b.x); o[5]=f2bf(b.y); o[6]=f2bf(b.z); o[7]=f2bf(b.w);
      *(s8v*)&wob[i] = o;
    } else if (aux < 2560) {
      // cache_k f32 [0,PP) -> bf16 keys
      int idx = (aux - 2048) * 256 + tid;
      int bkv = idx >> 13;
      int rem = idx & 8191;
      size_t off = (size_t)bkv * (CTX * HD) + (size_t)rem * 8;
      float4 a = *(const float4*)&ck[off];
      float4 b = *(const float4*)&ck[off + 4];
      s8v o;
      o[0]=f2bf(a.x); o[1]=f2bf(a.y); o[2]=f2bf(a.z); o[3]=f2bf(a.w);
      o[4]=f2bf(b.x); o[5]=f2bf(b.y); o[6]=f2bf(b.z); o[7]=f2bf(b.w);
      *(s8v*)&keys[off] = o;
    } else {
      // cache_v [0,PP) -> valsT (permuted key order within 64-blocks)
      short (*Ts)[72] = (short (*)[72])&As[0][0];   // reuse GEMM LDS
      const int blk2 = aux - 2560;              // B*KVH*(PP/64) = 256
      const int bkv = blk2 >> 4;
      const int p0  = (blk2 & 15) * 64;
      const float* src = cv + (size_t)bkv * CTX * HD + (size_t)p0 * HD;
      {
        int dq = tid & 15, kb = tid >> 4;
        float4 vv[4];
#pragma unroll
        for (int i = 0; i < 4; i++)
          vv[i] = *(const float4*)&src[(size_t)(kb * 4 + i) * HD + dq * 4];
#pragma unroll
        for (int j = 0; j < 4; j++) {
          s4v p;
          p[0]=f2bf(((const float*)&vv[0])[j]); p[1]=f2bf(((const float*)&vv[1])[j]);
          p[2]=f2bf(((const float*)&vv[2])[j]); p[3]=f2bf(((const float*)&vv[3])[j]);
          *(s4v*)&Ts[dq * 4 + j][kb * 4] = p;
        }
      }
      __syncthreads();
      {
        int d = tid >> 2, c = tid & 3;
        short* dst = vt + ((size_t)bkv * HD + d) * CTX + p0 + (c >> 1) * 32 + (c & 1) * 4;
#pragma unroll
        for (int j = 0; j < 4; j++) {
          s4v q4 = *(const s4v*)&Ts[d][c * 16 + j * 4];
          *(s4v*)&dst[j * 8] = q4;
        }
      }
    }
    return;
  }

  // ------------------------------ GEMM blocks ------------------------------
  // XCD-chunk swizzle (bijective since 384 % 8 == 0): consecutive tiles of
  // one M-band land on ONE XCD -> A-panel fetched once per XCD.
  const int swz = (id & 7) * 48 + (id >> 3);
  const int wv   = tid >> 6, lane = tid & 63;
  const int wm   = wv & 1, wn = wv >> 1;
  const int n16  = lane & 15, g = lane >> 4;
  const int m0   = (swz / 24) * 128, n0 = (swz % 24) * 128;
  const int K = 2048;

  const int rr = tid >> 3;                          // 0..31 rows per stage step
  const int cc = ((tid & 7) ^ (rr & 7)) * 8;        // pre-swizzled col chunk
  const short* pA = A  + (size_t)(m0 + rr) * K + cc;
  const short* pB = Bw + (size_t)(n0 + rr) * K + cc;

  auto stage = [&](int buf, int kofs) {
#pragma unroll
    for (int st = 0; st < 4; st++) {
      gl_lds16(pA + kofs + (size_t)st * 32 * K, &As[buf][(st * 256 + wv * 64) * 8]);
      gl_lds16(pB + kofs + (size_t)st * 32 * K, &Bs[buf][(st * 256 + wv * 64) * 8]);
    }
  };

  f4v acc[4][4] = {};
  stage(0, 0);
  int cur = 0;
  for (int k0 = 0; k0 < K; k0 += 64) {
    __syncthreads();                       // buf[cur] ready (drain after compute)
    if (k0 + 64 < K) stage(cur ^ 1, k0 + 64);

#pragma unroll
    for (int kk = 0; kk < 2; kk++) {
      s8v af[4], bf[4];
#pragma unroll
      for (int mt = 0; mt < 4; mt++)
        af[mt] = *(const s8v*)&As[cur][(wm * 64 + mt * 16 + n16) * 64 + (((kk << 2) | g) ^ (n16 & 7)) * 8];
#pragma unroll
      for (int nt = 0; nt < 4; nt++)
        bf[nt] = *(const s8v*)&Bs[cur][(wn * 64 + nt * 16 + n16) * 64 + (((kk << 2) | g) ^ (n16 & 7)) * 8];
#pragma unroll
      for (int mt = 0; mt < 4; mt++)
#pragma unroll
        for (int nt = 0; nt < 4; nt++)
          acc[mt][nt] = __builtin_amdgcn_mfma_f32_16x16x32_bf16(af[mt], bf[nt], acc[mt][nt], 0, 0, 0);
    }
    cur ^= 1;
  }

  const int rowb = m0 + wm * 64 + g * 4;
  const int colb = n0 + wn * 64 + n16;
  if (n0 < 2048) {
    // Q region -> qb (B,S,E) bf16
#pragma unroll
    for (int mt = 0; mt < 4; mt++)
#pragma unroll
      for (int nt = 0; nt < 4; nt++) {
        size_t base = (size_t)(rowb + mt * 16) * E + colb + nt * 16;
#pragma unroll
        for (int r = 0; r < 4; r++)
          qb[base + (size_t)r * E] = f2bf(acc[mt][nt][r]);
      }
  } else if (n0 < 2560) {
    // K region: RoPE in-register (f32), scatter into keys at pos PP+s.
    const int kvh = ((n0 - 2048) >> 6) + wn;
#pragma unroll
    for (int mt = 0; mt < 4; mt++) {
      const int row = rowb + mt * 16;          // in [0, B*S)
      const int bb = row >> 10, s = row & 1023;
      const float* crow = cosb + ((size_t)bb * S + s) * HD;
      const float* srow = sinb + ((size_t)bb * S + s) * HD;
      const size_t kdst = (((size_t)bb * KVH + kvh) * CTX + PP + s) * HD;
#pragma unroll
      for (int nt = 0; nt < 2; nt++) {
        const int d = n16 + nt * 16;
#pragma unroll
        for (int r = 0; r < 4; r++) {
          float c  = crow[r * HD + d];
          float sn = srow[r * HD + d];
          float k1 = acc[mt][nt][r], k2 = acc[mt][nt + 2][r];
          keys[kdst + (size_t)r * HD + d]      = f2bf(k1 * c - k2 * sn);
          keys[kdst + (size_t)r * HD + d + 32] = f2bf(k2 * c + k1 * sn);
        }
      }
    }
  } else {
    // V region -> valsT[(bkv*HD+d)*CTX + PP + perm(s)]
    const int b    = m0 >> 10;
    const int head = ((n0 - 2560) >> 6) + wn;
    const int sbase = (m0 - (b << 10)) + wm * 64;   // multiple of 64
    const size_t vrowb = (size_t)(b * KVH + head) * HD;
#pragma unroll
    for (int mt = 0; mt < 4; mt++) {
      const int pos = PP + sbase + ((mt >> 1) << 5) + ((mt & 1) << 2) + (g << 3);
#pragma unroll
      for (int nt = 0; nt < 4; nt++) {
        const int d = nt * 16 + n16;
        s4v o;
        o[0] = f2bf(acc[mt][nt][0]); o[1] = f2bf(acc[mt][nt][1]);
        o[2] = f2bf(acc[mt][nt][2]); o[3] = f2bf(acc[mt][nt][3]);
        *(s4v*)&vt[(vrowb + d) * CTX + pos] = o;
      }
    }
  }
}

// ---------------------------------------------------------------------------
// bf16 MFMA GEMM, BK=64, 2-phase double-buffered staging, split-K=2,
// atomic f32 accumulate (for O-proj). 1D grid 512, XCD-chunk swizzled
// within each K-half (bijective, 256 = 8*32).
// ---------------------------------------------------------------------------
__global__ __launch_bounds__(256) void gemm_bf16_sk(const short* __restrict__ A,
                                                    const short* __restrict__ Bw,
                                                    float* __restrict__ C,
                                                    int M, int N, int K) {
  __shared__ short As[2][8192];
  __shared__ short Bs[2][8192];
  const int tid  = threadIdx.x;
  const int wv   = tid >> 6, lane = tid & 63;
  const int wm   = wv & 1, wn = wv >> 1;
  const int n16  = lane & 15, g = lane >> 4;
  const int id   = blockIdx.x;
  const int z    = id >> 8;                       // K-half
  const int r0i  = id & 255;
  const int swz  = (r0i & 7) * 32 + (r0i >> 3);   // XCD chunk swizzle
  const int m0   = (swz >> 4) * 128, n0 = (swz & 15) * 128;
  const int kh   = K >> 1;
  const int kbeg = z * kh;

  const int rr = tid >> 3;
  const int cc = ((tid & 7) ^ (rr & 7)) * 8;
  const short* pA = A  + (size_t)(m0 + rr) * K + kbeg + cc;
  const short* pB = Bw + (size_t)(n0 + rr) * K + kbeg + cc;

  auto stage = [&](int buf, int kofs) {
#pragma unroll
    for (int st = 0; st < 4; st++) {
      gl_lds16(pA + kofs + (size_t)st * 32 * K, &As[buf][(st * 256 + wv * 64) * 8]);
      gl_lds16(pB + kofs + (size_t)st * 32 * K, &Bs[buf][(st * 256 + wv * 64) * 8]);
    }
  };

  f4v acc[4][4] = {};
  stage(0, 0);
  int cur = 0;
  for (int k0 = 0; k0 < kh; k0 += 64) {
    __syncthreads();
    if (k0 + 64 < kh) stage(cur ^ 1, k0 + 64);

#pragma unroll
    for (int kk = 0; kk < 2; kk++) {
      s8v af[4], bf[4];
#pragma unroll
      for (int mt = 0; mt < 4; mt++)
        af[mt] = *(const s8v*)&As[cur][(wm * 64 + mt * 16 + n16) * 64 + (((kk << 2) | g) ^ (n16 & 7)) * 8];
#pragma unroll
      for (int nt = 0; nt < 4; nt++)
        bf[nt] = *(const s8v*)&Bs[cur][(wn * 64 + nt * 16 + n16) * 64 + (((kk << 2) | g) ^ (n16 & 7)) * 8];
#pragma unroll
      for (int mt = 0; mt < 4; mt++)
#pragma unroll
        for (int nt = 0; nt < 4; nt++)
          acc[mt][nt] = __builtin_amdgcn_mfma_f32_16x16x32_bf16(af[mt], bf[nt], acc[mt][nt], 0, 0, 0);
    }
    cur ^= 1;
  }

#pragma unroll
  for (int mt = 0; mt < 4; mt++)
#pragma unroll
    for (int nt = 0; nt < 4; nt++) {
      size_t base = (size_t)(m0 + wm * 64 + mt * 16 + g * 4) * N + n0 + wn * 64 + nt * 16 + n16;
#pragma unroll
      for (int r = 0; r < 4; r++)
        unsafeAtomicAdd(&C[base + (size_t)r * N], acc[mt][nt][r]);
    }
}

// ---------------------------------------------------------------------------
// MFMA flash attention (R1/R7-measured structure: single-buffered, 16KB LDS)
// + s_setprio around MFMA clusters. 1024 blocks (b,h,sblk), 4 waves,
// 16 q-rows/wave. exp2 softmax with no max-bias, cvt_pk bf16 packing,
// 4 parallel l-chains, gl_lds chunk-XOR swizzle (0-conflict).
// NOTE: 6 structural variants measured (pairing 65, dbuf 60.7, ctx-split
// 72.5, 2-wave 66.5) — all lose to this via occupancy/TLP. Do not rewrite.
// ---------------------------------------------------------------------------
__global__ __launch_bounds__(256) void attn_mfma(const short* __restrict__ qb,
                                                 const float* __restrict__ cosb,
                                                 const float* __restrict__ sinb,
                                                 const short* __restrict__ keys,
                                                 const short* __restrict__ valsT,
                                                 short* __restrict__ attn) {
  __shared__ short Ks[4096];    // K tile [key][dim] 64x64, chunk-swizzled
  __shared__ short VTs[4096];   // V^T tile [dim][permuted key], chunk-swizzled

  const int sblk = 15 - (blockIdx.x & 15);     // long blocks first
  const int h    = (blockIdx.x >> 4) & (H - 1);
  const int b    = blockIdx.x >> 9;
  const int kv   = h >> 2;
  const int sq0  = sblk * 64;
  const int kend = PP + sq0 + 64;

  const int tid  = threadIdx.x;
  const int w    = tid >> 6;
  const int lane = tid & 63;
  const int n    = lane & 15;
  const int g    = lane >> 4;

  const short* kbase = keys  + ((size_t)b * KVH + kv) * CTX * HD;
  const short* vtb   = valsT + ((size_t)b * KVH + kv) * (size_t)HD * CTX;

  // ---- Q frags: bf16 in, RoPE fused, scale = 0.125*log2(e) ----
  union { s4v h4[2]; s8v v; } qlo, qhi;
  {
    const size_t row = (size_t)b * S + sq0 + w * 16 + n;
    const short* qrow = qb + row * E + h * 64;
    const float* crow = cosb + row * HD;
    const float* srow = sinb + row * HD;
    const float SC = 0.18033688011112042f;   // 0.125 * log2(e)
    s8v q0 = *(const s8v*)&qrow[g * 8];
    s8v q1 = *(const s8v*)&qrow[32 + g * 8];
    float cc[8], ss[8];
    *(float4*)&cc[0] = *(const float4*)&crow[g * 8];
    *(float4*)&cc[4] = *(const float4*)&crow[g * 8 + 4];
    *(float4*)&ss[0] = *(const float4*)&srow[g * 8];
    *(float4*)&ss[4] = *(const float4*)&srow[g * 8 + 4];
#pragma unroll
    for (int j = 0; j < 8; j++) {
      float fl = bf2f(q0[j]), fh = bf2f(q1[j]);
      qlo.v[j] = f2bf((fl * cc[j] - fh * ss[j]) * SC);
      qhi.v[j] = f2bf((fh * cc[j] + fl * ss[j]) * SC);
    }
  }

  f4v O[4] = {{0,0,0,0},{0,0,0,0},{0,0,0,0},{0,0,0,0}};
  float la[4] = {0.f, 0.f, 0.f, 0.f};          // 4 parallel l-chains
  const int qp     = PP + sq0 + w * 16 + n;    // this lane's query position
  const int qmin_w = PP + sq0 + w * 16;        // wave's min query position

  // gl_lds staging: wave w stages rows w*8..w*8+7 (+32) of each 64x64 tile;
  // lane: row = w*8 + (lane>>3), chunk slot lane&7 holds global chunk slot^row
  const int lrow = lane >> 3;
  const int sw   = (lane & 7) ^ lrow;
  const short* kg0 = kbase + (size_t)(w * 8 + lrow) * HD + sw * 8;
  const short* kg1 = kg0 + 32 * HD;
  const short* vg0 = vtb + (size_t)(w * 8 + lrow) * CTX + sw * 8;
  const short* vg1 = vg0 + (size_t)32 * CTX;
  short* kl0 = Ks + w * 512;
  short* kl1 = Ks + 2048 + w * 512;
  short* vl0 = VTs + w * 512;
  short* vl1 = VTs + 2048 + w * 512;

  const int xsl = (g ^ (n & 7)) * 8;   // swizzled frag slot (lo); hi = ^32

  for (int k0 = 0; k0 < kend; k0 += 64) {
    __syncthreads();
    gl_lds16(kg0 + (size_t)k0 * HD, kl0);
    gl_lds16(kg1 + (size_t)k0 * HD, kl1);
    gl_lds16(vg0 + k0, vl0);
    gl_lds16(vg1 + k0, vl1);
    __syncthreads();

    if (k0 >= qmin_w + 16) continue;   // wave's K-range done (barriers aligned)

    // ---- S^T = K_tile @ Q^T (scores in log2 units) ----
    f4v sc[4];
    __builtin_amdgcn_s_setprio(1);
#pragma unroll
    for (int st = 0; st < 4; st++) {
      const short* krow = &Ks[(st * 16 + n) * 64];
      s8v alo = *(const s8v*)(krow + xsl);
      s8v ahi = *(const s8v*)(krow + (xsl ^ 32));
      f4v z = {0.f, 0.f, 0.f, 0.f};
      z = __builtin_amdgcn_mfma_f32_16x16x32_bf16(alo, qlo.v, z, 0, 0, 0);
      sc[st] = __builtin_amdgcn_mfma_f32_16x16x32_bf16(ahi, qhi.v, z, 0, 0, 0);
    }
    __builtin_amdgcn_s_setprio(0);

    // ---- causal mask near diagonal ----
    if (k0 + 63 > qmin_w) {
#pragma unroll
      for (int st = 0; st < 4; st++)
#pragma unroll
        for (int r = 0; r < 4; r++) {
          int kpos = k0 + st * 16 + g * 4 + r;
          if (kpos > qp) sc[st][r] = -3e38f;
        }
    }

    // ---- exp2 softmax; P^T packed into PV B-operand regs via cvt_pk ----
    union { unsigned u[4]; s8v v; } pb0, pb1;
#pragma unroll
    for (int st = 0; st < 4; st++) {
      float e0 = __builtin_amdgcn_exp2f(sc[st][0]);
      float e1 = __builtin_amdgcn_exp2f(sc[st][1]);
      float e2 = __builtin_amdgcn_exp2f(sc[st][2]);
      float e3 = __builtin_amdgcn_exp2f(sc[st][3]);
      la[0] += e0; la[1] += e1; la[2] += e2; la[3] += e3;
      unsigned w0, w1;
      asm("v_cvt_pk_bf16_f32 %0, %1, %2" : "=v"(w0) : "v"(e0), "v"(e1));
      asm("v_cvt_pk_bf16_f32 %0, %1, %2" : "=v"(w1) : "v"(e2), "v"(e3));
      if (st < 2) { pb0.u[st * 2] = w0; pb0.u[st * 2 + 1] = w1; }
      else        { pb1.u[(st - 2) * 2] = w0; pb1.u[(st - 2) * 2 + 1] = w1; }
    }

    // ---- O^T += V^T @ P ----
    __builtin_amdgcn_s_setprio(1);
#pragma unroll
    for (int dg = 0; dg < 4; dg++) {
      const short* vr = &VTs[(dg * 16 + n) * 64];
      s8v va = *(const s8v*)(vr + xsl);
      s8v vx = *(const s8v*)(vr + (xsl ^ 32));
      O[dg] = __builtin_amdgcn_mfma_f32_16x16x32_bf16(va, pb0.v, O[dg], 0, 0, 0);
      O[dg] = __builtin_amdgcn_mfma_f32_16x16x32_bf16(vx, pb1.v, O[dg], 0, 0, 0);
    }
    __builtin_amdgcn_s_setprio(0);
  }

  // ---- reduce l across 4 g-lanes per query, normalize, store ----
  float l = (la[0] + la[1]) + (la[2] + la[3]);
  l += __shfl_xor(l, 16);
  l += __shfl_xor(l, 32);
  const float rl = 1.f / l;
  short* orow = attn + ((size_t)b * S + sq0 + w * 16 + n) * E + h * 64;
#pragma unroll
  for (int dg = 0; dg < 4; dg++) {
    s4v o;
    o[0] = f2bf(O[dg][0] * rl); o[1] = f2bf(O[dg][1] * rl);
    o[2] = f2bf(O[dg][2] * rl); o[3] = f2bf(O[dg][3] * rl);
    *(s4v*)&orow[dg * 16 + g * 4] = o;
  }
}

// ---------------------------------------------------------------------------
extern "C" void kernel_launch(void* const* d_in, const int* in_sizes, int n_in,
                              void* d_out, int out_size, void* d_ws, size_t ws_size,
                              hipStream_t stream) {
  const float* x       = (const float*)d_in[0];
  const float* cosb    = (const float*)d_in[1];
  const float* sinb    = (const float*)d_in[2];
  const float* cache_k = (const float*)d_in[4];
  const float* cache_v = (const float*)d_in[5];
  const float* Wq      = (const float*)d_in[6];
  const float* Wk      = (const float*)d_in[7];
  const float* Wv      = (const float*)d_in[8];
  const float* Wo      = (const float*)d_in[9];
  float* out = (float*)d_out;

  short* xb    = (short*)d_ws;                 // 4,194,304
  short* wqkv  = xb + 4194304;                 // 6,291,456
  short* wob   = wqkv + 6291456;               // 4,194,304
  short* keysb = wob + 4194304;                // 2,097,152
  short* valsT = keysb + 2097152;              // 2,097,152 (permuted V^T)
  short* aout  = valsT + 2097152;              // 4,194,304
  short* qb    = aout + 4194304;               // 4,194,304  (~55 MB total)

  dim3 blk(256);

  // 0) zero f32 out for O-proj split-K atomics (stream-ordered, capturable)
  hipMemsetAsync(out, 0, (size_t)out_size, stream);

  // 1) converts qkv_gemm depends on (x, Wq, Wk, Wv)
  prep<<<5120, blk, 0, stream>>>(x, Wq, Wk, Wv, xb, wqkv);

  // 2) fused QKV projection (384 GEMM blocks, XCD-swizzled) + aux prep
  //    (2816 blocks: Wo convert, cache_k, vT_old) filling idle CUs
  qkv_gemm<<<3200, blk, 0, stream>>>(xb, wqkv, cosb, sinb, Wo, cache_k, cache_v,
                                     qb, keysb, valsT, wob);

  // 3) attention (R1/R7 structure) -> bf16 (B,S,E)
  attn_mfma<<<B * H * (S / 64), blk, 0, stream>>>(qb, cosb, sinb, keysb, valsT, aout);

  // 4) output projection, split-K=2, XCD-swizzled 1D grid -> f32 out
  gemm_bf16_sk<<<512, blk, 0, stream>>>(aout, wob, out, B * S, E, E);
}

// Round 10
// 243.378 us; speedup vs baseline: 1.0838x; 1.0502x over previous
//
#include <hip/hip_runtime.h>
#include <cstddef>

#define B   2
#define S   1024
#define PP  1024          // start_pos
#define CTX 2048
#define E   2048
#define H   32
#define KVH 8
#define HD  64
#define GQ  4             // H / KVH
#define NQKV 3072         // E + 2*KVH*HD

typedef short s4v  __attribute__((ext_vector_type(4)));
typedef short s8v  __attribute__((ext_vector_type(8)));
typedef float f4v  __attribute__((ext_vector_type(4)));

__device__ __forceinline__ short f2bf(float f) {   // RNE f32 -> bf16
  union { float f; unsigned u; } v; v.f = f;
  unsigned r = v.u + 0x7fffu + ((v.u >> 16) & 1u);
  return (short)(r >> 16);
}
__device__ __forceinline__ float bf2f(short h) {
  union { unsigned u; float f; } v; v.u = ((unsigned)(unsigned short)h) << 16;
  return v.f;
}

__device__ __forceinline__ void gl_lds16(const void* g, void* l) {
  // async 16B/lane global->LDS; LDS dest = wave-uniform base + lane*16
  __builtin_amdgcn_global_load_lds((const __attribute__((address_space(1))) unsigned*)g,
                                   (__attribute__((address_space(3))) unsigned*)l, 16, 0, 0);
}

// ---------------------------------------------------------------------------
// prep: only the sections qkv_gemm DEPENDS on (x + Wq/Wk/Wv converts).
// [0,2048) x | [2048,4096) Wq | [4096,4608) Wk | [4608,5120) Wv
// ---------------------------------------------------------------------------
__global__ __launch_bounds__(256) void prep(const float* __restrict__ x,
                                            const float* __restrict__ Wq,
                                            const float* __restrict__ Wk,
                                            const float* __restrict__ Wv,
                                            short* __restrict__ xb,
                                            short* __restrict__ wqkv) {
  const int blk = blockIdx.x, tid = threadIdx.x;
  const float* s; short* d; int base;
  if (blk < 2048)      { s = x;  d = xb;             base = blk; }
  else if (blk < 4096) { s = Wq; d = wqkv;           base = blk - 2048; }
  else if (blk < 4608) { s = Wk; d = wqkv + 4194304; base = blk - 4096; }
  else                 { s = Wv; d = wqkv + 5242880; base = blk - 4608; }
  int i = (base * 256 + tid) * 8;
  float4 a = *(const float4*)&s[i];
  float4 b = *(const float4*)&s[i + 4];
  s8v o;
  o[0]=f2bf(a.x); o[1]=f2bf(a.y); o[2]=f2bf(a.z); o[3]=f2bf(a.w);
  o[4]=f2bf(b.x); o[5]=f2bf(b.y); o[6]=f2bf(b.z); o[7]=f2bf(b.w);
  *(s8v*)&d[i] = o;
}

// ---------------------------------------------------------------------------
// QKV GEMM (ids [0,384)) + aux prep blocks (ids [384,4224)).
// GEMM: BK=64, 2-phase dbuf staging, fused epilogue (q bf16; K RoPE'd
// in-register -> keys; V -> permuted valsT).
// Aux: [0,2048) Wo convert | [2048,2560) cache_k | [2560,2816) vT_old |
//      [2816,3840) zero out. These fill CUs idle during the 384-block GEMM.
// ---------------------------------------------------------------------------
__global__ __launch_bounds__(256) void qkv_gemm(const short* __restrict__ A,
                                                const short* __restrict__ Bw,
                                                const float* __restrict__ cosb,
                                                const float* __restrict__ sinb,
                                                const float* __restrict__ Wo,
                                                const float* __restrict__ ck,
                                                const float* __restrict__ cv,
                                                short* __restrict__ qb,
                                                short* __restrict__ keys,
                                                short* __restrict__ vt,
                                                short* __restrict__ wob,
                                                float4* __restrict__ outz) {
  __shared__ short As[2][8192];
  __shared__ short Bs[2][8192];
  const int tid = threadIdx.x;
  const int id  = blockIdx.x;

  if (id >= 384) {                     // ---------- aux prep blocks ----------
    const int aux = id - 384;
    if (aux < 2048) {
      // Wo f32 -> bf16
      int i = (aux * 256 + tid) * 8;
      float4 a = *(const float4*)&Wo[i];
      float4 b = *(const float4*)&Wo[i + 4];
      s8v o;
      o[0]=f2bf(a.x); o[1]=f2bf(a.y); o[2]=f2bf(a.z); o[3]=f2bf(a.w);
      o[4]=f2bf(b.x); o[5]=f2bf(b.y); o[6]=f2bf(b.z); o[7]=f2bf(b.w);
      *(s8v*)&wob[i] = o;
    } else if (aux < 2560) {
      // cache_k f32 [0,PP) -> bf16 keys
      int idx = (aux - 2048) * 256 + tid;
      int bkv = idx >> 13;
      int rem = idx & 8191;
      size_t off = (size_t)bkv * (CTX * HD) + (size_t)rem * 8;
      float4 a = *(const float4*)&ck[off];
      float4 b = *(const float4*)&ck[off + 4];
      s8v o;
      o[0]=f2bf(a.x); o[1]=f2bf(a.y); o[2]=f2bf(a.z); o[3]=f2bf(a.w);
      o[4]=f2bf(b.x); o[5]=f2bf(b.y); o[6]=f2bf(b.z); o[7]=f2bf(b.w);
      *(s8v*)&keys[off] = o;
    } else if (aux < 2816) {
      // cache_v [0,PP) -> valsT (permuted key order within 64-blocks)
      short (*Ts)[72] = (short (*)[72])&As[0][0];   // reuse GEMM LDS
      const int blk2 = aux - 2560;              // B*KVH*(PP/64) = 256
      const int bkv = blk2 >> 4;
      const int p0  = (blk2 & 15) * 64;
      const float* src = cv + (size_t)bkv * CTX * HD + (size_t)p0 * HD;
      {
        int dq = tid & 15, kb = tid >> 4;
        float4 vv[4];
#pragma unroll
        for (int i = 0; i < 4; i++)
          vv[i] = *(const float4*)&src[(size_t)(kb * 4 + i) * HD + dq * 4];
#pragma unroll
        for (int j = 0; j < 4; j++) {
          s4v p;
          p[0]=f2bf(((const float*)&vv[0])[j]); p[1]=f2bf(((const float*)&vv[1])[j]);
          p[2]=f2bf(((const float*)&vv[2])[j]); p[3]=f2bf(((const float*)&vv[3])[j]);
          *(s4v*)&Ts[dq * 4 + j][kb * 4] = p;
        }
      }
      __syncthreads();
      {
        int d = tid >> 2, c = tid & 3;
        short* dst = vt + ((size_t)bkv * HD + d) * CTX + p0 + (c >> 1) * 32 + (c & 1) * 4;
#pragma unroll
        for (int j = 0; j < 4; j++) {
          s4v q4 = *(const s4v*)&Ts[d][c * 16 + j * 4];
          *(s4v*)&dst[j * 8] = q4;
        }
      }
    } else {
      // zero f32 out (4,194,304 floats) for O-proj split-K atomics
      int i0 = (aux - 2816) * 1024 + tid * 4;
#pragma unroll
      for (int j = 0; j < 4; j++) outz[i0 + j] = make_float4(0.f, 0.f, 0.f, 0.f);
    }
    return;
  }

  // ------------------------------ GEMM blocks ------------------------------
  const int wv   = tid >> 6, lane = tid & 63;
  const int wm   = wv & 1, wn = wv >> 1;
  const int n16  = lane & 15, g = lane >> 4;
  const int m0   = (id / 24) * 128, n0 = (id % 24) * 128;
  const int K = 2048;

  const int rr = tid >> 3;                          // 0..31 rows per stage step
  const int cc = ((tid & 7) ^ (rr & 7)) * 8;        // pre-swizzled col chunk
  const short* pA = A  + (size_t)(m0 + rr) * K + cc;
  const short* pB = Bw + (size_t)(n0 + rr) * K + cc;

  auto stage = [&](int buf, int kofs) {
#pragma unroll
    for (int st = 0; st < 4; st++) {
      gl_lds16(pA + kofs + (size_t)st * 32 * K, &As[buf][(st * 256 + wv * 64) * 8]);
      gl_lds16(pB + kofs + (size_t)st * 32 * K, &Bs[buf][(st * 256 + wv * 64) * 8]);
    }
  };

  f4v acc[4][4] = {};
  stage(0, 0);
  int cur = 0;
  for (int k0 = 0; k0 < K; k0 += 64) {
    __syncthreads();                       // buf[cur] ready (drain after compute)
    if (k0 + 64 < K) stage(cur ^ 1, k0 + 64);

#pragma unroll
    for (int kk = 0; kk < 2; kk++) {
      s8v af[4], bf[4];
#pragma unroll
      for (int mt = 0; mt < 4; mt++)
        af[mt] = *(const s8v*)&As[cur][(wm * 64 + mt * 16 + n16) * 64 + (((kk << 2) | g) ^ (n16 & 7)) * 8];
#pragma unroll
      for (int nt = 0; nt < 4; nt++)
        bf[nt] = *(const s8v*)&Bs[cur][(wn * 64 + nt * 16 + n16) * 64 + (((kk << 2) | g) ^ (n16 & 7)) * 8];
#pragma unroll
      for (int mt = 0; mt < 4; mt++)
#pragma unroll
        for (int nt = 0; nt < 4; nt++)
          acc[mt][nt] = __builtin_amdgcn_mfma_f32_16x16x32_bf16(af[mt], bf[nt], acc[mt][nt], 0, 0, 0);
    }
    cur ^= 1;
  }

  const int rowb = m0 + wm * 64 + g * 4;
  const int colb = n0 + wn * 64 + n16;
  if (n0 < 2048) {
    // Q region -> qb (B,S,E) bf16
#pragma unroll
    for (int mt = 0; mt < 4; mt++)
#pragma unroll
      for (int nt = 0; nt < 4; nt++) {
        size_t base = (size_t)(rowb + mt * 16) * E + colb + nt * 16;
#pragma unroll
        for (int r = 0; r < 4; r++)
          qb[base + (size_t)r * E] = f2bf(acc[mt][nt][r]);
      }
  } else if (n0 < 2560) {
    // K region: RoPE in-register (f32), scatter into keys at pos PP+s.
    const int kvh = ((n0 - 2048) >> 6) + wn;
#pragma unroll
    for (int mt = 0; mt < 4; mt++) {
      const int row = rowb + mt * 16;          // in [0, B*S)
      const int bb = row >> 10, s = row & 1023;
      const float* crow = cosb + ((size_t)bb * S + s) * HD;
      const float* srow = sinb + ((size_t)bb * S + s) * HD;
      const size_t kdst = (((size_t)bb * KVH + kvh) * CTX + PP + s) * HD;
#pragma unroll
      for (int nt = 0; nt < 2; nt++) {
        const int d = n16 + nt * 16;
#pragma unroll
        for (int r = 0; r < 4; r++) {
          float c  = crow[r * HD + d];
          float sn = srow[r * HD + d];
          float k1 = acc[mt][nt][r], k2 = acc[mt][nt + 2][r];
          keys[kdst + (size_t)r * HD + d]      = f2bf(k1 * c - k2 * sn);
          keys[kdst + (size_t)r * HD + d + 32] = f2bf(k2 * c + k1 * sn);
        }
      }
    }
  } else {
    // V region -> valsT[(bkv*HD+d)*CTX + PP + perm(s)]
    const int b    = m0 >> 10;
    const int head = ((n0 - 2560) >> 6) + wn;
    const int sbase = (m0 - (b << 10)) + wm * 64;   // multiple of 64
    const size_t vrowb = (size_t)(b * KVH + head) * HD;
#pragma unroll
    for (int mt = 0; mt < 4; mt++) {
      const int pos = PP + sbase + ((mt >> 1) << 5) + ((mt & 1) << 2) + (g << 3);
#pragma unroll
      for (int nt = 0; nt < 4; nt++) {
        const int d = nt * 16 + n16;
        s4v o;
        o[0] = f2bf(acc[mt][nt][0]); o[1] = f2bf(acc[mt][nt][1]);
        o[2] = f2bf(acc[mt][nt][2]); o[3] = f2bf(acc[mt][nt][3]);
        *(s4v*)&vt[(vrowb + d) * CTX + pos] = o;
      }
    }
  }
}

// ---------------------------------------------------------------------------
// bf16 MFMA GEMM, BK=64, 2-phase double-buffered staging, split-K=2,
// atomic f32 accumulate (for O-proj).
// ---------------------------------------------------------------------------
__global__ __launch_bounds__(256) void gemm_bf16_sk(const short* __restrict__ A,
                                                    const short* __restrict__ Bw,
                                                    float* __restrict__ C,
                                                    int M, int N, int K) {
  __shared__ short As[2][8192];
  __shared__ short Bs[2][8192];
  const int tid  = threadIdx.x;
  const int wv   = tid >> 6, lane = tid & 63;
  const int wm   = wv & 1, wn = wv >> 1;
  const int n16  = lane & 15, g = lane >> 4;
  const int m0   = blockIdx.y * 128, n0 = blockIdx.x * 128;
  const int kh   = K >> 1;
  const int kbeg = blockIdx.z * kh;

  const int rr = tid >> 3;
  const int cc = ((tid & 7) ^ (rr & 7)) * 8;
  const short* pA = A  + (size_t)(m0 + rr) * K + kbeg + cc;
  const short* pB = Bw + (size_t)(n0 + rr) * K + kbeg + cc;

  auto stage = [&](int buf, int kofs) {
#pragma unroll
    for (int st = 0; st < 4; st++) {
      gl_lds16(pA + kofs + (size_t)st * 32 * K, &As[buf][(st * 256 + wv * 64) * 8]);
      gl_lds16(pB + kofs + (size_t)st * 32 * K, &Bs[buf][(st * 256 + wv * 64) * 8]);
    }
  };

  f4v acc[4][4] = {};
  stage(0, 0);
  int cur = 0;
  for (int k0 = 0; k0 < kh; k0 += 64) {
    __syncthreads();
    if (k0 + 64 < kh) stage(cur ^ 1, k0 + 64);

#pragma unroll
    for (int kk = 0; kk < 2; kk++) {
      s8v af[4], bf[4];
#pragma unroll
      for (int mt = 0; mt < 4; mt++)
        af[mt] = *(const s8v*)&As[cur][(wm * 64 + mt * 16 + n16) * 64 + (((kk << 2) | g) ^ (n16 & 7)) * 8];
#pragma unroll
      for (int nt = 0; nt < 4; nt++)
        bf[nt] = *(const s8v*)&Bs[cur][(wn * 64 + nt * 16 + n16) * 64 + (((kk << 2) | g) ^ (n16 & 7)) * 8];
#pragma unroll
      for (int mt = 0; mt < 4; mt++)
#pragma unroll
        for (int nt = 0; nt < 4; nt++)
          acc[mt][nt] = __builtin_amdgcn_mfma_f32_16x16x32_bf16(af[mt], bf[nt], acc[mt][nt], 0, 0, 0);
    }
    cur ^= 1;
  }

#pragma unroll
  for (int mt = 0; mt < 4; mt++)
#pragma unroll
    for (int nt = 0; nt < 4; nt++) {
      size_t base = (size_t)(m0 + wm * 64 + mt * 16 + g * 4) * N + n0 + wn * 64 + nt * 16 + n16;
#pragma unroll
      for (int r = 0; r < 4; r++)
        unsafeAtomicAdd(&C[base + (size_t)r * N], acc[mt][nt][r]);
    }
}

// ---------------------------------------------------------------------------
// MFMA flash attention (R1/R7-measured structure: single-buffered, 16KB LDS)
// + s_setprio around MFMA clusters. 1024 blocks, 4 waves, 16 q-rows/wave.
// Block decode is XCD-locality mapped: blockIdx&7 (the XCD under round-robin
// dispatch) selects a 2-pair (b,kv) group, so each XCD's K/V staging slice
// is 2.1 MB < 4 MiB L2 (vs all-16-pairs 8.4 MB before) — gl_lds staging
// sources from the local L2 instead of L3. Long sblk first within each XCD.
// exp2 softmax (no max-bias), cvt_pk packing, 4 parallel l-chains, chunk-XOR
// swizzle (0-conflict). 6 structural variants measured and rejected
// (pairing 65, dbuf 60.7, ctx-split 72.5, 2-wave 66.5) — do not rewrite.
// ---------------------------------------------------------------------------
__global__ __launch_bounds__(256) void attn_mfma(const short* __restrict__ qb,
                                                 const float* __restrict__ cosb,
                                                 const float* __restrict__ sinb,
                                                 const short* __restrict__ keys,
                                                 const short* __restrict__ valsT,
                                                 short* __restrict__ attn) {
  __shared__ short Ks[4096];    // K tile [key][dim] 64x64, chunk-swizzled
  __shared__ short VTs[4096];   // V^T tile [dim][permuted key], chunk-swizzled

  // XCD-locality decode: xcd = id&7 owns (b,kv) pairs {2*xcd, 2*xcd+1}
  const int xcd  = blockIdx.x & 7;
  const int j    = blockIdx.x >> 3;            // 0..127 within XCD
  const int sblk = 15 - (j >> 3);              // long blocks first
  const int bkv  = xcd * 2 + ((j >> 2) & 1);
  const int b    = bkv >> 3;
  const int kv   = bkv & 7;
  const int h    = kv * 4 + (j & 3);
  const int sq0  = sblk * 64;
  const int kend = PP + sq0 + 64;

  const int tid  = threadIdx.x;
  const int w    = tid >> 6;
  const int lane = tid & 63;
  const int n    = lane & 15;
  const int g    = lane >> 4;

  const short* kbase = keys  + ((size_t)b * KVH + kv) * CTX * HD;
  const short* vtb   = valsT + ((size_t)b * KVH + kv) * (size_t)HD * CTX;

  // ---- Q frags: bf16 in, RoPE fused, scale = 0.125*log2(e) ----
  union { s4v h4[2]; s8v v; } qlo, qhi;
  {
    const size_t row = (size_t)b * S + sq0 + w * 16 + n;
    const short* qrow = qb + row * E + h * 64;
    const float* crow = cosb + row * HD;
    const float* srow = sinb + row * HD;
    const float SC = 0.18033688011112042f;   // 0.125 * log2(e)
    s8v q0 = *(const s8v*)&qrow[g * 8];
    s8v q1 = *(const s8v*)&qrow[32 + g * 8];
    float cc[8], ss[8];
    *(float4*)&cc[0] = *(const float4*)&crow[g * 8];
    *(float4*)&cc[4] = *(const float4*)&crow[g * 8 + 4];
    *(float4*)&ss[0] = *(const float4*)&srow[g * 8];
    *(float4*)&ss[4] = *(const float4*)&srow[g * 8 + 4];
#pragma unroll
    for (int j2 = 0; j2 < 8; j2++) {
      float fl = bf2f(q0[j2]), fh = bf2f(q1[j2]);
      qlo.v[j2] = f2bf((fl * cc[j2] - fh * ss[j2]) * SC);
      qhi.v[j2] = f2bf((fh * cc[j2] + fl * ss[j2]) * SC);
    }
  }

  f4v O[4] = {{0,0,0,0},{0,0,0,0},{0,0,0,0},{0,0,0,0}};
  float la[4] = {0.f, 0.f, 0.f, 0.f};          // 4 parallel l-chains
  const int qp     = PP + sq0 + w * 16 + n;    // this lane's query position
  const int qmin_w = PP + sq0 + w * 16;        // wave's min query position

  // gl_lds staging: wave w stages rows w*8..w*8+7 (+32) of each 64x64 tile;
  // lane: row = w*8 + (lane>>3), chunk slot lane&7 holds global chunk slot^row
  const int lrow = lane >> 3;
  const int sw   = (lane & 7) ^ lrow;
  const short* kg0 = kbase + (size_t)(w * 8 + lrow) * HD + sw * 8;
  const short* kg1 = kg0 + 32 * HD;
  const short* vg0 = vtb + (size_t)(w * 8 + lrow) * CTX + sw * 8;
  const short* vg1 = vg0 + (size_t)32 * CTX;
  short* kl0 = Ks + w * 512;
  short* kl1 = Ks + 2048 + w * 512;
  short* vl0 = VTs + w * 512;
  short* vl1 = VTs + 2048 + w * 512;

  const int xsl = (g ^ (n & 7)) * 8;   // swizzled frag slot (lo); hi = ^32

  for (int k0 = 0; k0 < kend; k0 += 64) {
    __syncthreads();
    gl_lds16(kg0 + (size_t)k0 * HD, kl0);
    gl_lds16(kg1 + (size_t)k0 * HD, kl1);
    gl_lds16(vg0 + k0, vl0);
    gl_lds16(vg1 + k0, vl1);
    __syncthreads();

    if (k0 >= qmin_w + 16) continue;   // wave's K-range done (barriers aligned)

    // ---- S^T = K_tile @ Q^T (scores in log2 units) ----
    f4v sc[4];
    __builtin_amdgcn_s_setprio(1);
#pragma unroll
    for (int st = 0; st < 4; st++) {
      const short* krow = &Ks[(st * 16 + n) * 64];
      s8v alo = *(const s8v*)(krow + xsl);
      s8v ahi = *(const s8v*)(krow + (xsl ^ 32));
      f4v z = {0.f, 0.f, 0.f, 0.f};
      z = __builtin_amdgcn_mfma_f32_16x16x32_bf16(alo, qlo.v, z, 0, 0, 0);
      sc[st] = __builtin_amdgcn_mfma_f32_16x16x32_bf16(ahi, qhi.v, z, 0, 0, 0);
    }
    __builtin_amdgcn_s_setprio(0);

    // ---- causal mask near diagonal ----
    if (k0 + 63 > qmin_w) {
#pragma unroll
      for (int st = 0; st < 4; st++)
#pragma unroll
        for (int r = 0; r < 4; r++) {
          int kpos = k0 + st * 16 + g * 4 + r;
          if (kpos > qp) sc[st][r] = -3e38f;
        }
    }

    // ---- exp2 softmax; P^T packed into PV B-operand regs via cvt_pk ----
    union { unsigned u[4]; s8v v; } pb0, pb1;
#pragma unroll
    for (int st = 0; st < 4; st++) {
      float e0 = __builtin_amdgcn_exp2f(sc[st][0]);
      float e1 = __builtin_amdgcn_exp2f(sc[st][1]);
      float e2 = __builtin_amdgcn_exp2f(sc[st][2]);
      float e3 = __builtin_amdgcn_exp2f(sc[st][3]);
      la[0] += e0; la[1] += e1; la[2] += e2; la[3] += e3;
      unsigned w0, w1;
      asm("v_cvt_pk_bf16_f32 %0, %1, %2" : "=v"(w0) : "v"(e0), "v"(e1));
      asm("v_cvt_pk_bf16_f32 %0, %1, %2" : "=v"(w1) : "v"(e2), "v"(e3));
      if (st < 2) { pb0.u[st * 2] = w0; pb0.u[st * 2 + 1] = w1; }
      else        { pb1.u[(st - 2) * 2] = w0; pb1.u[(st - 2) * 2 + 1] = w1; }
    }

    // ---- O^T += V^T @ P ----
    __builtin_amdgcn_s_setprio(1);
#pragma unroll
    for (int dg = 0; dg < 4; dg++) {
      const short* vr = &VTs[(dg * 16 + n) * 64];
      s8v va = *(const s8v*)(vr + xsl);
      s8v vx = *(const s8v*)(vr + (xsl ^ 32));
      O[dg] = __builtin_amdgcn_mfma_f32_16x16x32_bf16(va, pb0.v, O[dg], 0, 0, 0);
      O[dg] = __builtin_amdgcn_mfma_f32_16x16x32_bf16(vx, pb1.v, O[dg], 0, 0, 0);
    }
    __builtin_amdgcn_s_setprio(0);
  }

  // ---- reduce l across 4 g-lanes per query, normalize, store ----
  float l = (la[0] + la[1]) + (la[2] + la[3]);
  l += __shfl_xor(l, 16);
  l += __shfl_xor(l, 32);
  const float rl = 1.f / l;
  short* orow = attn + ((size_t)b * S + sq0 + w * 16 + n) * E + h * 64;
#pragma unroll
  for (int dg = 0; dg < 4; dg++) {
    s4v o;
    o[0] = f2bf(O[dg][0] * rl); o[1] = f2bf(O[dg][1] * rl);
    o[2] = f2bf(O[dg][2] * rl); o[3] = f2bf(O[dg][3] * rl);
    *(s4v*)&orow[dg * 16 + g * 4] = o;
  }
}

// ---------------------------------------------------------------------------
extern "C" void kernel_launch(void* const* d_in, const int* in_sizes, int n_in,
                              void* d_out, int out_size, void* d_ws, size_t ws_size,
                              hipStream_t stream) {
  const float* x       = (const float*)d_in[0];
  const float* cosb    = (const float*)d_in[1];
  const float* sinb    = (const float*)d_in[2];
  const float* cache_k = (const float*)d_in[4];
  const float* cache_v = (const float*)d_in[5];
  const float* Wq      = (const float*)d_in[6];
  const float* Wk      = (const float*)d_in[7];
  const float* Wv      = (const float*)d_in[8];
  const float* Wo      = (const float*)d_in[9];
  float* out = (float*)d_out;

  short* xb    = (short*)d_ws;                 // 4,194,304
  short* wqkv  = xb + 4194304;                 // 6,291,456
  short* wob   = wqkv + 6291456;               // 4,194,304
  short* keysb = wob + 4194304;                // 2,097,152
  short* valsT = keysb + 2097152;              // 2,097,152 (permuted V^T)
  short* aout  = valsT + 2097152;              // 4,194,304
  short* qb    = aout + 4194304;               // 4,194,304  (~55 MB total)

  dim3 blk(256);

  // 1) converts qkv_gemm depends on (x, Wq, Wk, Wv)
  prep<<<5120, blk, 0, stream>>>(x, Wq, Wk, Wv, xb, wqkv);

  // 2) fused QKV projection (384 GEMM blocks) + aux prep (3840 blocks:
  //    Wo convert, cache_k, vT_old, zero-out) filling idle CUs
  qkv_gemm<<<4224, blk, 0, stream>>>(xb, wqkv, cosb, sinb, Wo, cache_k, cache_v,
                                     qb, keysb, valsT, wob, (float4*)out);

  // 3) attention (R7 structure, XCD-locality block decode) -> bf16 (B,S,E)
  attn_mfma<<<B * H * (S / 64), blk, 0, stream>>>(qb, cosb, sinb, keysb, valsT, aout);

  // 4) output projection, split-K=2 -> f32 out (zeroed in qkv aux)
  gemm_bf16_sk<<<dim3(E / 128, (B * S) / 128, 2), blk, 0, stream>>>(aout, wob, out, B * S, E, E);
}

// Round 11
// 229.374 us; speedup vs baseline: 1.1499x; 1.0611x over previous
//
#include <hip/hip_runtime.h>
#include <cstddef>

#define B   2
#define S   1024
#define PP  1024          // start_pos
#define CTX 2048
#define E   2048
#define H   32
#define KVH 8
#define HD  64
#define GQ  4             // H / KVH
#define NQKV 3072         // E + 2*KVH*HD

typedef short s4v  __attribute__((ext_vector_type(4)));
typedef short s8v  __attribute__((ext_vector_type(8)));
typedef float f4v  __attribute__((ext_vector_type(4)));

__device__ __forceinline__ short f2bf(float f) {   // RNE f32 -> bf16
  union { float f; unsigned u; } v; v.f = f;
  unsigned r = v.u + 0x7fffu + ((v.u >> 16) & 1u);
  return (short)(r >> 16);
}
__device__ __forceinline__ float bf2f(short h) {
  union { unsigned u; float f; } v; v.u = ((unsigned)(unsigned short)h) << 16;
  return v.f;
}

__device__ __forceinline__ void gl_lds16(const void* g, void* l) {
  // async 16B/lane global->LDS; LDS dest = wave-uniform base + lane*16
  __builtin_amdgcn_global_load_lds((const __attribute__((address_space(1))) unsigned*)g,
                                   (__attribute__((address_space(3))) unsigned*)l, 16, 0, 0);
}

// ---------------------------------------------------------------------------
// prep: only the sections qkv_gemm DEPENDS on (x + Wq/Wk/Wv converts).
// [0,2048) x | [2048,4096) Wq | [4096,4608) Wk | [4608,5120) Wv
// ---------------------------------------------------------------------------
__global__ __launch_bounds__(256) void prep(const float* __restrict__ x,
                                            const float* __restrict__ Wq,
                                            const float* __restrict__ Wk,
                                            const float* __restrict__ Wv,
                                            short* __restrict__ xb,
                                            short* __restrict__ wqkv) {
  const int blk = blockIdx.x, tid = threadIdx.x;
  const float* s; short* d; int base;
  if (blk < 2048)      { s = x;  d = xb;             base = blk; }
  else if (blk < 4096) { s = Wq; d = wqkv;           base = blk - 2048; }
  else if (blk < 4608) { s = Wk; d = wqkv + 4194304; base = blk - 4096; }
  else                 { s = Wv; d = wqkv + 5242880; base = blk - 4608; }
  int i = (base * 256 + tid) * 8;
  float4 a = *(const float4*)&s[i];
  float4 b = *(const float4*)&s[i + 4];
  s8v o;
  o[0]=f2bf(a.x); o[1]=f2bf(a.y); o[2]=f2bf(a.z); o[3]=f2bf(a.w);
  o[4]=f2bf(b.x); o[5]=f2bf(b.y); o[6]=f2bf(b.z); o[7]=f2bf(b.w);
  *(s8v*)&d[i] = o;
}

// ---------------------------------------------------------------------------
// QKV GEMM (ids [0,768)) + aux prep blocks (ids [768,3584)).
// GEMM: 128x64 tiles (BM=128, BN=64, BK=64, dbuf 48KB -> 3 blocks/CU,
// grid 768 = exactly 3/CU), 2-phase dbuf staging, 4 waves of 32 rows x
// 64 cols (acc 2x4). BN=64 keeps RoPE pairs (d,d+32) within one wave.
// Fused epilogue: q bf16; K RoPE'd in-register -> keys; V -> permuted valsT.
// Aux: [0,2048) Wo convert | [2048,2560) cache_k | [2560,2816) vT_old.
// (no zero-out: oproj now stores f32 directly, no atomics)
// ---------------------------------------------------------------------------
__global__ __launch_bounds__(256) void qkv_gemm(const short* __restrict__ A,
                                                const short* __restrict__ Bw,
                                                const float* __restrict__ cosb,
                                                const float* __restrict__ sinb,
                                                const float* __restrict__ Wo,
                                                const float* __restrict__ ck,
                                                const float* __restrict__ cv,
                                                short* __restrict__ qb,
                                                short* __restrict__ keys,
                                                short* __restrict__ vt,
                                                short* __restrict__ wob) {
  __shared__ short As[2][8192];    // 128 x 64
  __shared__ short Bs[2][4096];    // 64 x 64
  const int tid = threadIdx.x;
  const int id  = blockIdx.x;

  if (id >= 768) {                     // ---------- aux prep blocks ----------
    const int aux = id - 768;
    if (aux < 2048) {
      // Wo f32 -> bf16
      int i = (aux * 256 + tid) * 8;
      float4 a = *(const float4*)&Wo[i];
      float4 b = *(const float4*)&Wo[i + 4];
      s8v o;
      o[0]=f2bf(a.x); o[1]=f2bf(a.y); o[2]=f2bf(a.z); o[3]=f2bf(a.w);
      o[4]=f2bf(b.x); o[5]=f2bf(b.y); o[6]=f2bf(b.z); o[7]=f2bf(b.w);
      *(s8v*)&wob[i] = o;
    } else if (aux < 2560) {
      // cache_k f32 [0,PP) -> bf16 keys
      int idx = (aux - 2048) * 256 + tid;
      int bkv = idx >> 13;
      int rem = idx & 8191;
      size_t off = (size_t)bkv * (CTX * HD) + (size_t)rem * 8;
      float4 a = *(const float4*)&ck[off];
      float4 b = *(const float4*)&ck[off + 4];
      s8v o;
      o[0]=f2bf(a.x); o[1]=f2bf(a.y); o[2]=f2bf(a.z); o[3]=f2bf(a.w);
      o[4]=f2bf(b.x); o[5]=f2bf(b.y); o[6]=f2bf(b.z); o[7]=f2bf(b.w);
      *(s8v*)&keys[off] = o;
    } else {
      // cache_v [0,PP) -> valsT (permuted key order within 64-blocks)
      short (*Ts)[72] = (short (*)[72])&As[0][0];   // reuse GEMM LDS (9KB<16KB)
      const int blk2 = aux - 2560;              // B*KVH*(PP/64) = 256
      const int bkv = blk2 >> 4;
      const int p0  = (blk2 & 15) * 64;
      const float* src = cv + (size_t)bkv * CTX * HD + (size_t)p0 * HD;
      {
        int dq = tid & 15, kb = tid >> 4;
        float4 vv[4];
#pragma unroll
        for (int i = 0; i < 4; i++)
          vv[i] = *(const float4*)&src[(size_t)(kb * 4 + i) * HD + dq * 4];
#pragma unroll
        for (int j = 0; j < 4; j++) {
          s4v p;
          p[0]=f2bf(((const float*)&vv[0])[j]); p[1]=f2bf(((const float*)&vv[1])[j]);
          p[2]=f2bf(((const float*)&vv[2])[j]); p[3]=f2bf(((const float*)&vv[3])[j]);
          *(s4v*)&Ts[dq * 4 + j][kb * 4] = p;
        }
      }
      __syncthreads();
      {
        int d = tid >> 2, c = tid & 3;
        short* dst = vt + ((size_t)bkv * HD + d) * CTX + p0 + (c >> 1) * 32 + (c & 1) * 4;
#pragma unroll
        for (int j = 0; j < 4; j++) {
          s4v q4 = *(const s4v*)&Ts[d][c * 16 + j * 4];
          *(s4v*)&dst[j * 8] = q4;
        }
      }
    }
    return;
  }

  // ------------------------------ GEMM blocks ------------------------------
  const int wv   = tid >> 6, lane = tid & 63;
  const int n16  = lane & 15, g = lane >> 4;
  const int m0   = (id / 48) * 128, n0 = (id % 48) * 64;
  const int K = 2048;

  const int rr = tid >> 3;                          // 0..31 rows per stage step
  const int cc = ((tid & 7) ^ (rr & 7)) * 8;        // pre-swizzled col chunk
  const short* pA = A  + (size_t)(m0 + rr) * K + cc;
  const short* pB = Bw + (size_t)(n0 + rr) * K + cc;

  auto stage = [&](int buf, int kofs) {
#pragma unroll
    for (int st = 0; st < 4; st++)
      gl_lds16(pA + kofs + (size_t)st * 32 * K, &As[buf][(st * 256 + wv * 64) * 8]);
#pragma unroll
    for (int st = 0; st < 2; st++)
      gl_lds16(pB + kofs + (size_t)st * 32 * K, &Bs[buf][(st * 256 + wv * 64) * 8]);
  };

  f4v acc[2][4] = {};
  stage(0, 0);
  int cur = 0;
  for (int k0 = 0; k0 < K; k0 += 64) {
    __syncthreads();                       // buf[cur] ready (drain after compute)
    if (k0 + 64 < K) stage(cur ^ 1, k0 + 64);

#pragma unroll
    for (int kk = 0; kk < 2; kk++) {
      const int slot = (((kk << 2) | g) ^ (n16 & 7)) * 8;
      s8v af[2], bf[4];
#pragma unroll
      for (int mt = 0; mt < 2; mt++)
        af[mt] = *(const s8v*)&As[cur][(wv * 32 + mt * 16 + n16) * 64 + slot];
#pragma unroll
      for (int nt = 0; nt < 4; nt++)
        bf[nt] = *(const s8v*)&Bs[cur][(nt * 16 + n16) * 64 + slot];
#pragma unroll
      for (int mt = 0; mt < 2; mt++)
#pragma unroll
        for (int nt = 0; nt < 4; nt++)
          acc[mt][nt] = __builtin_amdgcn_mfma_f32_16x16x32_bf16(af[mt], bf[nt], acc[mt][nt], 0, 0, 0);
    }
    cur ^= 1;
  }

  const int rowb = m0 + wv * 32 + g * 4;
  if (n0 < 2048) {
    // Q region -> qb (B,S,E) bf16
#pragma unroll
    for (int mt = 0; mt < 2; mt++)
#pragma unroll
      for (int nt = 0; nt < 4; nt++) {
        size_t base = (size_t)(rowb + mt * 16) * E + n0 + nt * 16 + n16;
#pragma unroll
        for (int r = 0; r < 4; r++)
          qb[base + (size_t)r * E] = f2bf(acc[mt][nt][r]);
      }
  } else if (n0 < 2560) {
    // K region: RoPE in-register (f32), scatter into keys at pos PP+s.
    // Tile = exactly one head (64 cols). d = nt*16+n16; pairs (d,d+32) are
    // (nt, nt+2) — both in this wave since the wave holds all 64 cols.
    const int kvh = (n0 - 2048) >> 6;
#pragma unroll
    for (int mt = 0; mt < 2; mt++) {
      const int row = rowb + mt * 16;          // in [0, B*S)
      const int bb = row >> 10, s = row & 1023;
      const float* crow = cosb + ((size_t)bb * S + s) * HD;
      const float* srow = sinb + ((size_t)bb * S + s) * HD;
      const size_t kdst = (((size_t)bb * KVH + kvh) * CTX + PP + s) * HD;
#pragma unroll
      for (int nt = 0; nt < 2; nt++) {
        const int d = n16 + nt * 16;
#pragma unroll
        for (int r = 0; r < 4; r++) {
          float c  = crow[r * HD + d];
          float sn = srow[r * HD + d];
          float k1 = acc[mt][nt][r], k2 = acc[mt][nt + 2][r];
          keys[kdst + (size_t)r * HD + d]      = f2bf(k1 * c - k2 * sn);
          keys[kdst + (size_t)r * HD + d + 32] = f2bf(k2 * c + k1 * sn);
        }
      }
    }
  } else {
    // V region -> valsT[(bkv*HD+d)*CTX + PP + perm(s)]
    // Wave covers rows [wv*32, wv*32+32) = half of a 64-row perm block;
    // within-block index i = mtp*16 + g*4 + r with mtp = (wv&1)*2 + mt.
    const int b    = m0 >> 10;
    const int head = (n0 - 2560) >> 6;
    const int sbase = (m0 - (b << 10)) + (wv >> 1) * 64;
    const size_t vrowb = (size_t)(b * KVH + head) * HD;
#pragma unroll
    for (int mt = 0; mt < 2; mt++) {
      const int mtp = (wv & 1) * 2 + mt;
      const int pos = PP + sbase + ((mtp >> 1) << 5) + ((mtp & 1) << 2) + (g << 3);
#pragma unroll
      for (int nt = 0; nt < 4; nt++) {
        const int d = nt * 16 + n16;
        s4v o;
        o[0] = f2bf(acc[mt][nt][0]); o[1] = f2bf(acc[mt][nt][1]);
        o[2] = f2bf(acc[mt][nt][2]); o[3] = f2bf(acc[mt][nt][3]);
        *(s4v*)&vt[(vrowb + d) * CTX + pos] = o;
      }
    }
  }
}

// ---------------------------------------------------------------------------
// O-projection GEMM: 128x64 tiles, NO split-K, direct f32 stores (no
// atomics, no zero-init). Grid 512 = 2/CU uniform, BK=64 dbuf (48KB LDS).
// ---------------------------------------------------------------------------
__global__ __launch_bounds__(256) void oproj_gemm(const short* __restrict__ A,
                                                  const short* __restrict__ Bw,
                                                  float* __restrict__ C) {
  __shared__ short As[2][8192];    // 128 x 64
  __shared__ short Bs[2][4096];    // 64 x 64
  const int tid  = threadIdx.x;
  const int wv   = tid >> 6, lane = tid & 63;
  const int n16  = lane & 15, g = lane >> 4;
  const int id   = blockIdx.x;
  const int m0   = (id >> 5) * 128, n0 = (id & 31) * 64;
  const int K = E, N = E;

  const int rr = tid >> 3;
  const int cc = ((tid & 7) ^ (rr & 7)) * 8;
  const short* pA = A  + (size_t)(m0 + rr) * K + cc;
  const short* pB = Bw + (size_t)(n0 + rr) * K + cc;

  auto stage = [&](int buf, int kofs) {
#pragma unroll
    for (int st = 0; st < 4; st++)
      gl_lds16(pA + kofs + (size_t)st * 32 * K, &As[buf][(st * 256 + wv * 64) * 8]);
#pragma unroll
    for (int st = 0; st < 2; st++)
      gl_lds16(pB + kofs + (size_t)st * 32 * K, &Bs[buf][(st * 256 + wv * 64) * 8]);
  };

  f4v acc[2][4] = {};
  stage(0, 0);
  int cur = 0;
  for (int k0 = 0; k0 < K; k0 += 64) {
    __syncthreads();
    if (k0 + 64 < K) stage(cur ^ 1, k0 + 64);

#pragma unroll
    for (int kk = 0; kk < 2; kk++) {
      const int slot = (((kk << 2) | g) ^ (n16 & 7)) * 8;
      s8v af[2], bf[4];
#pragma unroll
      for (int mt = 0; mt < 2; mt++)
        af[mt] = *(const s8v*)&As[cur][(wv * 32 + mt * 16 + n16) * 64 + slot];
#pragma unroll
      for (int nt = 0; nt < 4; nt++)
        bf[nt] = *(const s8v*)&Bs[cur][(nt * 16 + n16) * 64 + slot];
#pragma unroll
      for (int mt = 0; mt < 2; mt++)
#pragma unroll
        for (int nt = 0; nt < 4; nt++)
          acc[mt][nt] = __builtin_amdgcn_mfma_f32_16x16x32_bf16(af[mt], bf[nt], acc[mt][nt], 0, 0, 0);
    }
    cur ^= 1;
  }

#pragma unroll
  for (int mt = 0; mt < 2; mt++)
#pragma unroll
    for (int nt = 0; nt < 4; nt++) {
      size_t base = (size_t)(m0 + wv * 32 + mt * 16 + g * 4) * N + n0 + nt * 16 + n16;
#pragma unroll
      for (int r = 0; r < 4; r++)
        C[base + (size_t)r * N] = acc[mt][nt][r];
    }
}

// ---------------------------------------------------------------------------
// MFMA flash attention (R1/R7-measured structure: single-buffered, 16KB LDS)
// + s_setprio around MFMA clusters. 1024 blocks, 4 waves, 16 q-rows/wave.
// Block decode is XCD-locality mapped (measured WIN R10: blockIdx&7 selects
// a 2-pair (b,kv) group, each XCD's K/V slice 2.1MB < 4MiB L2 so gl_lds
// staging hits local L2). exp2 softmax (no max-bias), cvt_pk packing,
// 4 parallel l-chains, chunk-XOR swizzle (0-conflict). 6 structural
// variants measured and rejected — do not rewrite.
// ---------------------------------------------------------------------------
__global__ __launch_bounds__(256) void attn_mfma(const short* __restrict__ qb,
                                                 const float* __restrict__ cosb,
                                                 const float* __restrict__ sinb,
                                                 const short* __restrict__ keys,
                                                 const short* __restrict__ valsT,
                                                 short* __restrict__ attn) {
  __shared__ short Ks[4096];    // K tile [key][dim] 64x64, chunk-swizzled
  __shared__ short VTs[4096];   // V^T tile [dim][permuted key], chunk-swizzled

  // XCD-locality decode: xcd = id&7 owns (b,kv) pairs {2*xcd, 2*xcd+1}
  const int xcd  = blockIdx.x & 7;
  const int j    = blockIdx.x >> 3;            // 0..127 within XCD
  const int sblk = 15 - (j >> 3);              // long blocks first
  const int bkv  = xcd * 2 + ((j >> 2) & 1);
  const int b    = bkv >> 3;
  const int kv   = bkv & 7;
  const int h    = kv * 4 + (j & 3);
  const int sq0  = sblk * 64;
  const int kend = PP + sq0 + 64;

  const int tid  = threadIdx.x;
  const int w    = tid >> 6;
  const int lane = tid & 63;
  const int n    = lane & 15;
  const int g    = lane >> 4;

  const short* kbase = keys  + ((size_t)b * KVH + kv) * CTX * HD;
  const short* vtb   = valsT + ((size_t)b * KVH + kv) * (size_t)HD * CTX;

  // ---- Q frags: bf16 in, RoPE fused, scale = 0.125*log2(e) ----
  union { s4v h4[2]; s8v v; } qlo, qhi;
  {
    const size_t row = (size_t)b * S + sq0 + w * 16 + n;
    const short* qrow = qb + row * E + h * 64;
    const float* crow = cosb + row * HD;
    const float* srow = sinb + row * HD;
    const float SC = 0.18033688011112042f;   // 0.125 * log2(e)
    s8v q0 = *(const s8v*)&qrow[g * 8];
    s8v q1 = *(const s8v*)&qrow[32 + g * 8];
    float cc[8], ss[8];
    *(float4*)&cc[0] = *(const float4*)&crow[g * 8];
    *(float4*)&cc[4] = *(const float4*)&crow[g * 8 + 4];
    *(float4*)&ss[0] = *(const float4*)&srow[g * 8];
    *(float4*)&ss[4] = *(const float4*)&srow[g * 8 + 4];
#pragma unroll
    for (int j2 = 0; j2 < 8; j2++) {
      float fl = bf2f(q0[j2]), fh = bf2f(q1[j2]);
      qlo.v[j2] = f2bf((fl * cc[j2] - fh * ss[j2]) * SC);
      qhi.v[j2] = f2bf((fh * cc[j2] + fl * ss[j2]) * SC);
    }
  }

  f4v O[4] = {{0,0,0,0},{0,0,0,0},{0,0,0,0},{0,0,0,0}};
  float la[4] = {0.f, 0.f, 0.f, 0.f};          // 4 parallel l-chains
  const int qp     = PP + sq0 + w * 16 + n;    // this lane's query position
  const int qmin_w = PP + sq0 + w * 16;        // wave's min query position

  // gl_lds staging: wave w stages rows w*8..w*8+7 (+32) of each 64x64 tile;
  // lane: row = w*8 + (lane>>3), chunk slot lane&7 holds global chunk slot^row
  const int lrow = lane >> 3;
  const int sw   = (lane & 7) ^ lrow;
  const short* kg0 = kbase + (size_t)(w * 8 + lrow) * HD + sw * 8;
  const short* kg1 = kg0 + 32 * HD;
  const short* vg0 = vtb + (size_t)(w * 8 + lrow) * CTX + sw * 8;
  const short* vg1 = vg0 + (size_t)32 * CTX;
  short* kl0 = Ks + w * 512;
  short* kl1 = Ks + 2048 + w * 512;
  short* vl0 = VTs + w * 512;
  short* vl1 = VTs + 2048 + w * 512;

  const int xsl = (g ^ (n & 7)) * 8;   // swizzled frag slot (lo); hi = ^32

  for (int k0 = 0; k0 < kend; k0 += 64) {
    __syncthreads();
    gl_lds16(kg0 + (size_t)k0 * HD, kl0);
    gl_lds16(kg1 + (size_t)k0 * HD, kl1);
    gl_lds16(vg0 + k0, vl0);
    gl_lds16(vg1 + k0, vl1);
    __syncthreads();

    if (k0 >= qmin_w + 16) continue;   // wave's K-range done (barriers aligned)

    // ---- S^T = K_tile @ Q^T (scores in log2 units) ----
    f4v sc[4];
    __builtin_amdgcn_s_setprio(1);
#pragma unroll
    for (int st = 0; st < 4; st++) {
      const short* krow = &Ks[(st * 16 + n) * 64];
      s8v alo = *(const s8v*)(krow + xsl);
      s8v ahi = *(const s8v*)(krow + (xsl ^ 32));
      f4v z = {0.f, 0.f, 0.f, 0.f};
      z = __builtin_amdgcn_mfma_f32_16x16x32_bf16(alo, qlo.v, z, 0, 0, 0);
      sc[st] = __builtin_amdgcn_mfma_f32_16x16x32_bf16(ahi, qhi.v, z, 0, 0, 0);
    }
    __builtin_amdgcn_s_setprio(0);

    // ---- causal mask near diagonal ----
    if (k0 + 63 > qmin_w) {
#pragma unroll
      for (int st = 0; st < 4; st++)
#pragma unroll
        for (int r = 0; r < 4; r++) {
          int kpos = k0 + st * 16 + g * 4 + r;
          if (kpos > qp) sc[st][r] = -3e38f;
        }
    }

    // ---- exp2 softmax; P^T packed into PV B-operand regs via cvt_pk ----
    union { unsigned u[4]; s8v v; } pb0, pb1;
#pragma unroll
    for (int st = 0; st < 4; st++) {
      float e0 = __builtin_amdgcn_exp2f(sc[st][0]);
      float e1 = __builtin_amdgcn_exp2f(sc[st][1]);
      float e2 = __builtin_amdgcn_exp2f(sc[st][2]);
      float e3 = __builtin_amdgcn_exp2f(sc[st][3]);
      la[0] += e0; la[1] += e1; la[2] += e2; la[3] += e3;
      unsigned w0, w1;
      asm("v_cvt_pk_bf16_f32 %0, %1, %2" : "=v"(w0) : "v"(e0), "v"(e1));
      asm("v_cvt_pk_bf16_f32 %0, %1, %2" : "=v"(w1) : "v"(e2), "v"(e3));
      if (st < 2) { pb0.u[st * 2] = w0; pb0.u[st * 2 + 1] = w1; }
      else        { pb1.u[(st - 2) * 2] = w0; pb1.u[(st - 2) * 2 + 1] = w1; }
    }

    // ---- O^T += V^T @ P ----
    __builtin_amdgcn_s_setprio(1);
#pragma unroll
    for (int dg = 0; dg < 4; dg++) {
      const short* vr = &VTs[(dg * 16 + n) * 64];
      s8v va = *(const s8v*)(vr + xsl);
      s8v vx = *(const s8v*)(vr + (xsl ^ 32));
      O[dg] = __builtin_amdgcn_mfma_f32_16x16x32_bf16(va, pb0.v, O[dg], 0, 0, 0);
      O[dg] = __builtin_amdgcn_mfma_f32_16x16x32_bf16(vx, pb1.v, O[dg], 0, 0, 0);
    }
    __builtin_amdgcn_s_setprio(0);
  }

  // ---- reduce l across 4 g-lanes per query, normalize, store ----
  float l = (la[0] + la[1]) + (la[2] + la[3]);
  l += __shfl_xor(l, 16);
  l += __shfl_xor(l, 32);
  const float rl = 1.f / l;
  short* orow = attn + ((size_t)b * S + sq0 + w * 16 + n) * E + h * 64;
#pragma unroll
  for (int dg = 0; dg < 4; dg++) {
    s4v o;
    o[0] = f2bf(O[dg][0] * rl); o[1] = f2bf(O[dg][1] * rl);
    o[2] = f2bf(O[dg][2] * rl); o[3] = f2bf(O[dg][3] * rl);
    *(s4v*)&orow[dg * 16 + g * 4] = o;
  }
}

// ---------------------------------------------------------------------------
extern "C" void kernel_launch(void* const* d_in, const int* in_sizes, int n_in,
                              void* d_out, int out_size, void* d_ws, size_t ws_size,
                              hipStream_t stream) {
  const float* x       = (const float*)d_in[0];
  const float* cosb    = (const float*)d_in[1];
  const float* sinb    = (const float*)d_in[2];
  const float* cache_k = (const float*)d_in[4];
  const float* cache_v = (const float*)d_in[5];
  const float* Wq      = (const float*)d_in[6];
  const float* Wk      = (const float*)d_in[7];
  const float* Wv      = (const float*)d_in[8];
  const float* Wo      = (const float*)d_in[9];
  float* out = (float*)d_out;

  short* xb    = (short*)d_ws;                 // 4,194,304
  short* wqkv  = xb + 4194304;                 // 6,291,456
  short* wob   = wqkv + 6291456;               // 4,194,304
  short* keysb = wob + 4194304;                // 2,097,152
  short* valsT = keysb + 2097152;              // 2,097,152 (permuted V^T)
  short* aout  = valsT + 2097152;              // 4,194,304
  short* qb    = aout + 4194304;               // 4,194,304  (~55 MB total)

  dim3 blk(256);

  // 1) converts qkv_gemm depends on (x, Wq, Wk, Wv)
  prep<<<5120, blk, 0, stream>>>(x, Wq, Wk, Wv, xb, wqkv);

  // 2) fused QKV projection (768 128x64 GEMM blocks = 3/CU) + aux prep
  //    (2816 blocks: Wo convert, cache_k, vT_old) filling idle CUs
  qkv_gemm<<<3584, blk, 0, stream>>>(xb, wqkv, cosb, sinb, Wo, cache_k, cache_v,
                                     qb, keysb, valsT, wob);

  // 3) attention (R10 structure, XCD-locality block decode) -> bf16 (B,S,E)
  attn_mfma<<<B * H * (S / 64), blk, 0, stream>>>(qb, cosb, sinb, keysb, valsT, aout);

  // 4) output projection, 128x64 tiles, direct f32 stores (no atomics)
  oproj_gemm<<<512, blk, 0, stream>>>(aout, wob, out);
}

// Round 12
// 223.095 us; speedup vs baseline: 1.1823x; 1.0281x over previous
//
#include <hip/hip_runtime.h>
#include <cstddef>

#define B   2
#define S   1024
#define PP  1024          // start_pos
#define CTX 2048
#define E   2048
#define H   32
#define KVH 8
#define HD  64
#define GQ  4             // H / KVH
#define NQKV 3072         // E + 2*KVH*HD

typedef short s4v  __attribute__((ext_vector_type(4)));
typedef short s8v  __attribute__((ext_vector_type(8)));
typedef float f4v  __attribute__((ext_vector_type(4)));

__device__ __forceinline__ short f2bf(float f) {   // RNE f32 -> bf16
  union { float f; unsigned u; } v; v.f = f;
  unsigned r = v.u + 0x7fffu + ((v.u >> 16) & 1u);
  return (short)(r >> 16);
}
__device__ __forceinline__ float bf2f(short h) {
  union { unsigned u; float f; } v; v.u = ((unsigned)(unsigned short)h) << 16;
  return v.f;
}

__device__ __forceinline__ void gl_lds16(const void* g, void* l) {
  // async 16B/lane global->LDS; LDS dest = wave-uniform base + lane*16
  __builtin_amdgcn_global_load_lds((const __attribute__((address_space(1))) unsigned*)g,
                                   (__attribute__((address_space(3))) unsigned*)l, 16, 0, 0);
}

// ---------------------------------------------------------------------------
// prep: only the sections qkv_gemm DEPENDS on (x + Wq/Wk/Wv converts).
// [0,2048) x | [2048,4096) Wq | [4096,4608) Wk | [4608,5120) Wv
// ---------------------------------------------------------------------------
__global__ __launch_bounds__(256) void prep(const float* __restrict__ x,
                                            const float* __restrict__ Wq,
                                            const float* __restrict__ Wk,
                                            const float* __restrict__ Wv,
                                            short* __restrict__ xb,
                                            short* __restrict__ wqkv) {
  const int blk = blockIdx.x, tid = threadIdx.x;
  const float* s; short* d; int base;
  if (blk < 2048)      { s = x;  d = xb;             base = blk; }
  else if (blk < 4096) { s = Wq; d = wqkv;           base = blk - 2048; }
  else if (blk < 4608) { s = Wk; d = wqkv + 4194304; base = blk - 4096; }
  else                 { s = Wv; d = wqkv + 5242880; base = blk - 4608; }
  int i = (base * 256 + tid) * 8;
  float4 a = *(const float4*)&s[i];
  float4 b = *(const float4*)&s[i + 4];
  s8v o;
  o[0]=f2bf(a.x); o[1]=f2bf(a.y); o[2]=f2bf(a.z); o[3]=f2bf(a.w);
  o[4]=f2bf(b.x); o[5]=f2bf(b.y); o[6]=f2bf(b.z); o[7]=f2bf(b.w);
  *(s8v*)&d[i] = o;
}

// ---------------------------------------------------------------------------
// QKV GEMM (ids [0,768)) + aux prep blocks (ids [768,3584)).
// GEMM: 128x64 tiles (BM=128, BN=64, BK=64, dbuf 48KB), 2-phase staging
// upgraded to COUNTED-VMCNT pipeline (T3/T4): 2 tiles in flight per wave
// (12 gl_lds), per-iter s_waitcnt vmcnt(6) waits only the CURRENT tile's 6
// loads (next tile's 6 stay in flight across the raw s_barrier), restage
// into the freed buffer after the bottom barrier. Never vmcnt(0) mid-loop.
// Correctness: each wave's pre-barrier wait covers its own writes to the
// buffer all waves are about to read; bottom barrier protects WAR reuse.
// Fused epilogue: q bf16; K RoPE'd in-register -> keys; V -> permuted valsT.
// Aux: [0,2048) Wo convert | [2048,2560) cache_k | [2560,2816) vT_old.
// ---------------------------------------------------------------------------
__global__ __launch_bounds__(256) void qkv_gemm(const short* __restrict__ A,
                                                const short* __restrict__ Bw,
                                                const float* __restrict__ cosb,
                                                const float* __restrict__ sinb,
                                                const float* __restrict__ Wo,
                                                const float* __restrict__ ck,
                                                const float* __restrict__ cv,
                                                short* __restrict__ qb,
                                                short* __restrict__ keys,
                                                short* __restrict__ vt,
                                                short* __restrict__ wob) {
  __shared__ short As[2][8192];    // 128 x 64
  __shared__ short Bs[2][4096];    // 64 x 64
  const int tid = threadIdx.x;
  const int id  = blockIdx.x;

  if (id >= 768) {                     // ---------- aux prep blocks ----------
    const int aux = id - 768;
    if (aux < 2048) {
      // Wo f32 -> bf16
      int i = (aux * 256 + tid) * 8;
      float4 a = *(const float4*)&Wo[i];
      float4 b = *(const float4*)&Wo[i + 4];
      s8v o;
      o[0]=f2bf(a.x); o[1]=f2bf(a.y); o[2]=f2bf(a.z); o[3]=f2bf(a.w);
      o[4]=f2bf(b.x); o[5]=f2bf(b.y); o[6]=f2bf(b.z); o[7]=f2bf(b.w);
      *(s8v*)&wob[i] = o;
    } else if (aux < 2560) {
      // cache_k f32 [0,PP) -> bf16 keys
      int idx = (aux - 2048) * 256 + tid;
      int bkv = idx >> 13;
      int rem = idx & 8191;
      size_t off = (size_t)bkv * (CTX * HD) + (size_t)rem * 8;
      float4 a = *(const float4*)&ck[off];
      float4 b = *(const float4*)&ck[off + 4];
      s8v o;
      o[0]=f2bf(a.x); o[1]=f2bf(a.y); o[2]=f2bf(a.z); o[3]=f2bf(a.w);
      o[4]=f2bf(b.x); o[5]=f2bf(b.y); o[6]=f2bf(b.z); o[7]=f2bf(b.w);
      *(s8v*)&keys[off] = o;
    } else {
      // cache_v [0,PP) -> valsT (permuted key order within 64-blocks)
      short (*Ts)[72] = (short (*)[72])&As[0][0];   // reuse GEMM LDS (9KB<16KB)
      const int blk2 = aux - 2560;              // B*KVH*(PP/64) = 256
      const int bkv = blk2 >> 4;
      const int p0  = (blk2 & 15) * 64;
      const float* src = cv + (size_t)bkv * CTX * HD + (size_t)p0 * HD;
      {
        int dq = tid & 15, kb = tid >> 4;
        float4 vv[4];
#pragma unroll
        for (int i = 0; i < 4; i++)
          vv[i] = *(const float4*)&src[(size_t)(kb * 4 + i) * HD + dq * 4];
#pragma unroll
        for (int j = 0; j < 4; j++) {
          s4v p;
          p[0]=f2bf(((const float*)&vv[0])[j]); p[1]=f2bf(((const float*)&vv[1])[j]);
          p[2]=f2bf(((const float*)&vv[2])[j]); p[3]=f2bf(((const float*)&vv[3])[j]);
          *(s4v*)&Ts[dq * 4 + j][kb * 4] = p;
        }
      }
      __syncthreads();
      {
        int d = tid >> 2, c = tid & 3;
        short* dst = vt + ((size_t)bkv * HD + d) * CTX + p0 + (c >> 1) * 32 + (c & 1) * 4;
#pragma unroll
        for (int j = 0; j < 4; j++) {
          s4v q4 = *(const s4v*)&Ts[d][c * 16 + j * 4];
          *(s4v*)&dst[j * 8] = q4;
        }
      }
    }
    return;
  }

  // ------------------------------ GEMM blocks ------------------------------
  const int wv   = tid >> 6, lane = tid & 63;
  const int n16  = lane & 15, g = lane >> 4;
  const int m0   = (id / 48) * 128, n0 = (id % 48) * 64;
  const int K = 2048;

  const int rr = tid >> 3;                          // 0..31 rows per stage step
  const int cc = ((tid & 7) ^ (rr & 7)) * 8;        // pre-swizzled col chunk
  const short* pA = A  + (size_t)(m0 + rr) * K + cc;
  const short* pB = Bw + (size_t)(n0 + rr) * K + cc;

  auto stage = [&](int buf, int kofs) {             // 6 gl_lds per wave
#pragma unroll
    for (int st = 0; st < 4; st++)
      gl_lds16(pA + kofs + (size_t)st * 32 * K, &As[buf][(st * 256 + wv * 64) * 8]);
#pragma unroll
    for (int st = 0; st < 2; st++)
      gl_lds16(pB + kofs + (size_t)st * 32 * K, &Bs[buf][(st * 256 + wv * 64) * 8]);
  };

  f4v acc[2][4] = {};
  stage(0, 0);
  stage(1, 64);
  int cur = 0;
  for (int k0 = 0; k0 < K; k0 += 64) {
    // wait ONLY this tile's 6 loads; next tile's 6 remain in flight
    if (k0 + 64 < K) asm volatile("s_waitcnt vmcnt(6)" ::: "memory");
    else             asm volatile("s_waitcnt vmcnt(0)" ::: "memory");
    __builtin_amdgcn_sched_barrier(0);
    __builtin_amdgcn_s_barrier();        // all waves' slices of buf[cur] landed

#pragma unroll
    for (int kk = 0; kk < 2; kk++) {
      const int slot = (((kk << 2) | g) ^ (n16 & 7)) * 8;
      s8v af[2], bf[4];
#pragma unroll
      for (int mt = 0; mt < 2; mt++)
        af[mt] = *(const s8v*)&As[cur][(wv * 32 + mt * 16 + n16) * 64 + slot];
#pragma unroll
      for (int nt = 0; nt < 4; nt++)
        bf[nt] = *(const s8v*)&Bs[cur][(nt * 16 + n16) * 64 + slot];
#pragma unroll
      for (int mt = 0; mt < 2; mt++)
#pragma unroll
        for (int nt = 0; nt < 4; nt++)
          acc[mt][nt] = __builtin_amdgcn_mfma_f32_16x16x32_bf16(af[mt], bf[nt], acc[mt][nt], 0, 0, 0);
    }

    __builtin_amdgcn_s_barrier();        // everyone done reading buf[cur]
    if (k0 + 128 < K) stage(cur, k0 + 128);
    cur ^= 1;
  }

  const int rowb = m0 + wv * 32 + g * 4;
  if (n0 < 2048) {
    // Q region -> qb (B,S,E) bf16
#pragma unroll
    for (int mt = 0; mt < 2; mt++)
#pragma unroll
      for (int nt = 0; nt < 4; nt++) {
        size_t base = (size_t)(rowb + mt * 16) * E + n0 + nt * 16 + n16;
#pragma unroll
        for (int r = 0; r < 4; r++)
          qb[base + (size_t)r * E] = f2bf(acc[mt][nt][r]);
      }
  } else if (n0 < 2560) {
    // K region: RoPE in-register (f32), scatter into keys at pos PP+s.
    const int kvh = (n0 - 2048) >> 6;
#pragma unroll
    for (int mt = 0; mt < 2; mt++) {
      const int row = rowb + mt * 16;          // in [0, B*S)
      const int bb = row >> 10, s = row & 1023;
      const float* crow = cosb + ((size_t)bb * S + s) * HD;
      const float* srow = sinb + ((size_t)bb * S + s) * HD;
      const size_t kdst = (((size_t)bb * KVH + kvh) * CTX + PP + s) * HD;
#pragma unroll
      for (int nt = 0; nt < 2; nt++) {
        const int d = n16 + nt * 16;
#pragma unroll
        for (int r = 0; r < 4; r++) {
          float c  = crow[r * HD + d];
          float sn = srow[r * HD + d];
          float k1 = acc[mt][nt][r], k2 = acc[mt][nt + 2][r];
          keys[kdst + (size_t)r * HD + d]      = f2bf(k1 * c - k2 * sn);
          keys[kdst + (size_t)r * HD + d + 32] = f2bf(k2 * c + k1 * sn);
        }
      }
    }
  } else {
    // V region -> valsT[(bkv*HD+d)*CTX + PP + perm(s)]
    const int b    = m0 >> 10;
    const int head = (n0 - 2560) >> 6;
    const int sbase = (m0 - (b << 10)) + (wv >> 1) * 64;
    const size_t vrowb = (size_t)(b * KVH + head) * HD;
#pragma unroll
    for (int mt = 0; mt < 2; mt++) {
      const int mtp = (wv & 1) * 2 + mt;
      const int pos = PP + sbase + ((mtp >> 1) << 5) + ((mtp & 1) << 2) + (g << 3);
#pragma unroll
      for (int nt = 0; nt < 4; nt++) {
        const int d = nt * 16 + n16;
        s4v o;
        o[0] = f2bf(acc[mt][nt][0]); o[1] = f2bf(acc[mt][nt][1]);
        o[2] = f2bf(acc[mt][nt][2]); o[3] = f2bf(acc[mt][nt][3]);
        *(s4v*)&vt[(vrowb + d) * CTX + pos] = o;
      }
    }
  }
}

// ---------------------------------------------------------------------------
// O-projection GEMM: 128x64 tiles, NO split-K, direct f32 stores.
// Same counted-vmcnt pipeline as qkv_gemm (2 tiles in flight, vmcnt(6)).
// Grid 512 = 2/CU uniform, BK=64 dbuf (48KB LDS).
// ---------------------------------------------------------------------------
__global__ __launch_bounds__(256) void oproj_gemm(const short* __restrict__ A,
                                                  const short* __restrict__ Bw,
                                                  float* __restrict__ C) {
  __shared__ short As[2][8192];    // 128 x 64
  __shared__ short Bs[2][4096];    // 64 x 64
  const int tid  = threadIdx.x;
  const int wv   = tid >> 6, lane = tid & 63;
  const int n16  = lane & 15, g = lane >> 4;
  const int id   = blockIdx.x;
  const int m0   = (id >> 5) * 128, n0 = (id & 31) * 64;
  const int K = E, N = E;

  const int rr = tid >> 3;
  const int cc = ((tid & 7) ^ (rr & 7)) * 8;
  const short* pA = A  + (size_t)(m0 + rr) * K + cc;
  const short* pB = Bw + (size_t)(n0 + rr) * K + cc;

  auto stage = [&](int buf, int kofs) {             // 6 gl_lds per wave
#pragma unroll
    for (int st = 0; st < 4; st++)
      gl_lds16(pA + kofs + (size_t)st * 32 * K, &As[buf][(st * 256 + wv * 64) * 8]);
#pragma unroll
    for (int st = 0; st < 2; st++)
      gl_lds16(pB + kofs + (size_t)st * 32 * K, &Bs[buf][(st * 256 + wv * 64) * 8]);
  };

  f4v acc[2][4] = {};
  stage(0, 0);
  stage(1, 64);
  int cur = 0;
  for (int k0 = 0; k0 < K; k0 += 64) {
    if (k0 + 64 < K) asm volatile("s_waitcnt vmcnt(6)" ::: "memory");
    else             asm volatile("s_waitcnt vmcnt(0)" ::: "memory");
    __builtin_amdgcn_sched_barrier(0);
    __builtin_amdgcn_s_barrier();

#pragma unroll
    for (int kk = 0; kk < 2; kk++) {
      const int slot = (((kk << 2) | g) ^ (n16 & 7)) * 8;
      s8v af[2], bf[4];
#pragma unroll
      for (int mt = 0; mt < 2; mt++)
        af[mt] = *(const s8v*)&As[cur][(wv * 32 + mt * 16 + n16) * 64 + slot];
#pragma unroll
      for (int nt = 0; nt < 4; nt++)
        bf[nt] = *(const s8v*)&Bs[cur][(nt * 16 + n16) * 64 + slot];
#pragma unroll
      for (int mt = 0; mt < 2; mt++)
#pragma unroll
        for (int nt = 0; nt < 4; nt++)
          acc[mt][nt] = __builtin_amdgcn_mfma_f32_16x16x32_bf16(af[mt], bf[nt], acc[mt][nt], 0, 0, 0);
    }

    __builtin_amdgcn_s_barrier();
    if (k0 + 128 < K) stage(cur, k0 + 128);
    cur ^= 1;
  }

#pragma unroll
  for (int mt = 0; mt < 2; mt++)
#pragma unroll
    for (int nt = 0; nt < 4; nt++) {
      size_t base = (size_t)(m0 + wv * 32 + mt * 16 + g * 4) * N + n0 + nt * 16 + n16;
#pragma unroll
      for (int r = 0; r < 4; r++)
        C[base + (size_t)r * N] = acc[mt][nt][r];
    }
}

// ---------------------------------------------------------------------------
// MFMA flash attention (R1/R7-measured structure: single-buffered, 16KB LDS)
// + s_setprio around MFMA clusters. 1024 blocks, 4 waves, 16 q-rows/wave.
// Block decode is XCD-locality mapped (measured WIN R10/R11: 58.5 -> 46.2us;
// blockIdx&7 selects a 2-pair (b,kv) group, each XCD's K/V slice 2.1MB <
// 4MiB L2 so gl_lds staging hits local L2). exp2 softmax (no max-bias),
// cvt_pk packing, 4 parallel l-chains, chunk-XOR swizzle (0-conflict).
// 6 structural variants measured and rejected — do not rewrite.
// ---------------------------------------------------------------------------
__global__ __launch_bounds__(256) void attn_mfma(const short* __restrict__ qb,
                                                 const float* __restrict__ cosb,
                                                 const float* __restrict__ sinb,
                                                 const short* __restrict__ keys,
                                                 const short* __restrict__ valsT,
                                                 short* __restrict__ attn) {
  __shared__ short Ks[4096];    // K tile [key][dim] 64x64, chunk-swizzled
  __shared__ short VTs[4096];   // V^T tile [dim][permuted key], chunk-swizzled

  // XCD-locality decode: xcd = id&7 owns (b,kv) pairs {2*xcd, 2*xcd+1}
  const int xcd  = blockIdx.x & 7;
  const int j    = blockIdx.x >> 3;            // 0..127 within XCD
  const int sblk = 15 - (j >> 3);              // long blocks first
  const int bkv  = xcd * 2 + ((j >> 2) & 1);
  const int b    = bkv >> 3;
  const int kv   = bkv & 7;
  const int h    = kv * 4 + (j & 3);
  const int sq0  = sblk * 64;
  const int kend = PP + sq0 + 64;

  const int tid  = threadIdx.x;
  const int w    = tid >> 6;
  const int lane = tid & 63;
  const int n    = lane & 15;
  const int g    = lane >> 4;

  const short* kbase = keys  + ((size_t)b * KVH + kv) * CTX * HD;
  const short* vtb   = valsT + ((size_t)b * KVH + kv) * (size_t)HD * CTX;

  // ---- Q frags: bf16 in, RoPE fused, scale = 0.125*log2(e) ----
  union { s4v h4[2]; s8v v; } qlo, qhi;
  {
    const size_t row = (size_t)b * S + sq0 + w * 16 + n;
    const short* qrow = qb + row * E + h * 64;
    const float* crow = cosb + row * HD;
    const float* srow = sinb + row * HD;
    const float SC = 0.18033688011112042f;   // 0.125 * log2(e)
    s8v q0 = *(const s8v*)&qrow[g * 8];
    s8v q1 = *(const s8v*)&qrow[32 + g * 8];
    float cc[8], ss[8];
    *(float4*)&cc[0] = *(const float4*)&crow[g * 8];
    *(float4*)&cc[4] = *(const float4*)&crow[g * 8 + 4];
    *(float4*)&ss[0] = *(const float4*)&srow[g * 8];
    *(float4*)&ss[4] = *(const float4*)&srow[g * 8 + 4];
#pragma unroll
    for (int j2 = 0; j2 < 8; j2++) {
      float fl = bf2f(q0[j2]), fh = bf2f(q1[j2]);
      qlo.v[j2] = f2bf((fl * cc[j2] - fh * ss[j2]) * SC);
      qhi.v[j2] = f2bf((fh * cc[j2] + fl * ss[j2]) * SC);
    }
  }

  f4v O[4] = {{0,0,0,0},{0,0,0,0},{0,0,0,0},{0,0,0,0}};
  float la[4] = {0.f, 0.f, 0.f, 0.f};          // 4 parallel l-chains
  const int qp     = PP + sq0 + w * 16 + n;    // this lane's query position
  const int qmin_w = PP + sq0 + w * 16;        // wave's min query position

  // gl_lds staging: wave w stages rows w*8..w*8+7 (+32) of each 64x64 tile;
  // lane: row = w*8 + (lane>>3), chunk slot lane&7 holds global chunk slot^row
  const int lrow = lane >> 3;
  const int sw   = (lane & 7) ^ lrow;
  const short* kg0 = kbase + (size_t)(w * 8 + lrow) * HD + sw * 8;
  const short* kg1 = kg0 + 32 * HD;
  const short* vg0 = vtb + (size_t)(w * 8 + lrow) * CTX + sw * 8;
  const short* vg1 = vg0 + (size_t)32 * CTX;
  short* kl0 = Ks + w * 512;
  short* kl1 = Ks + 2048 + w * 512;
  short* vl0 = VTs + w * 512;
  short* vl1 = VTs + 2048 + w * 512;

  const int xsl = (g ^ (n & 7)) * 8;   // swizzled frag slot (lo); hi = ^32

  for (int k0 = 0; k0 < kend; k0 += 64) {
    __syncthreads();
    gl_lds16(kg0 + (size_t)k0 * HD, kl0);
    gl_lds16(kg1 + (size_t)k0 * HD, kl1);
    gl_lds16(vg0 + k0, vl0);
    gl_lds16(vg1 + k0, vl1);
    __syncthreads();

    if (k0 >= qmin_w + 16) continue;   // wave's K-range done (barriers aligned)

    // ---- S^T = K_tile @ Q^T (scores in log2 units) ----
    f4v sc[4];
    __builtin_amdgcn_s_setprio(1);
#pragma unroll
    for (int st = 0; st < 4; st++) {
      const short* krow = &Ks[(st * 16 + n) * 64];
      s8v alo = *(const s8v*)(krow + xsl);
      s8v ahi = *(const s8v*)(krow + (xsl ^ 32));
      f4v z = {0.f, 0.f, 0.f, 0.f};
      z = __builtin_amdgcn_mfma_f32_16x16x32_bf16(alo, qlo.v, z, 0, 0, 0);
      sc[st] = __builtin_amdgcn_mfma_f32_16x16x32_bf16(ahi, qhi.v, z, 0, 0, 0);
    }
    __builtin_amdgcn_s_setprio(0);

    // ---- causal mask near diagonal ----
    if (k0 + 63 > qmin_w) {
#pragma unroll
      for (int st = 0; st < 4; st++)
#pragma unroll
        for (int r = 0; r < 4; r++) {
          int kpos = k0 + st * 16 + g * 4 + r;
          if (kpos > qp) sc[st][r] = -3e38f;
        }
    }

    // ---- exp2 softmax; P^T packed into PV B-operand regs via cvt_pk ----
    union { unsigned u[4]; s8v v; } pb0, pb1;
#pragma unroll
    for (int st = 0; st < 4; st++) {
      float e0 = __builtin_amdgcn_exp2f(sc[st][0]);
      float e1 = __builtin_amdgcn_exp2f(sc[st][1]);
      float e2 = __builtin_amdgcn_exp2f(sc[st][2]);
      float e3 = __builtin_amdgcn_exp2f(sc[st][3]);
      la[0] += e0; la[1] += e1; la[2] += e2; la[3] += e3;
      unsigned w0, w1;
      asm("v_cvt_pk_bf16_f32 %0, %1, %2" : "=v"(w0) : "v"(e0), "v"(e1));
      asm("v_cvt_pk_bf16_f32 %0, %1, %2" : "=v"(w1) : "v"(e2), "v"(e3));
      if (st < 2) { pb0.u[st * 2] = w0; pb0.u[st * 2 + 1] = w1; }
      else        { pb1.u[(st - 2) * 2] = w0; pb1.u[(st - 2) * 2 + 1] = w1; }
    }

    // ---- O^T += V^T @ P ----
    __builtin_amdgcn_s_setprio(1);
#pragma unroll
    for (int dg = 0; dg < 4; dg++) {
      const short* vr = &VTs[(dg * 16 + n) * 64];
      s8v va = *(const s8v*)(vr + xsl);
      s8v vx = *(const s8v*)(vr + (xsl ^ 32));
      O[dg] = __builtin_amdgcn_mfma_f32_16x16x32_bf16(va, pb0.v, O[dg], 0, 0, 0);
      O[dg] = __builtin_amdgcn_mfma_f32_16x16x32_bf16(vx, pb1.v, O[dg], 0, 0, 0);
    }
    __builtin_amdgcn_s_setprio(0);
  }

  // ---- reduce l across 4 g-lanes per query, normalize, store ----
  float l = (la[0] + la[1]) + (la[2] + la[3]);
  l += __shfl_xor(l, 16);
  l += __shfl_xor(l, 32);
  const float rl = 1.f / l;
  short* orow = attn + ((size_t)b * S + sq0 + w * 16 + n) * E + h * 64;
#pragma unroll
  for (int dg = 0; dg < 4; dg++) {
    s4v o;
    o[0] = f2bf(O[dg][0] * rl); o[1] = f2bf(O[dg][1] * rl);
    o[2] = f2bf(O[dg][2] * rl); o[3] = f2bf(O[dg][3] * rl);
    *(s4v*)&orow[dg * 16 + g * 4] = o;
  }
}

// ---------------------------------------------------------------------------
extern "C" void kernel_launch(void* const* d_in, const int* in_sizes, int n_in,
                              void* d_out, int out_size, void* d_ws, size_t ws_size,
                              hipStream_t stream) {
  const float* x       = (const float*)d_in[0];
  const float* cosb    = (const float*)d_in[1];
  const float* sinb    = (const float*)d_in[2];
  const float* cache_k = (const float*)d_in[4];
  const float* cache_v = (const float*)d_in[5];
  const float* Wq      = (const float*)d_in[6];
  const float* Wk      = (const float*)d_in[7];
  const float* Wv      = (const float*)d_in[8];
  const float* Wo      = (const float*)d_in[9];
  float* out = (float*)d_out;

  short* xb    = (short*)d_ws;                 // 4,194,304
  short* wqkv  = xb + 4194304;                 // 6,291,456
  short* wob   = wqkv + 6291456;               // 4,194,304
  short* keysb = wob + 4194304;                // 2,097,152
  short* valsT = keysb + 2097152;              // 2,097,152 (permuted V^T)
  short* aout  = valsT + 2097152;              // 4,194,304
  short* qb    = aout + 4194304;               // 4,194,304  (~55 MB total)

  dim3 blk(256);

  // 1) converts qkv_gemm depends on (x, Wq, Wk, Wv)
  prep<<<5120, blk, 0, stream>>>(x, Wq, Wk, Wv, xb, wqkv);

  // 2) fused QKV projection (768 128x64 GEMM blocks, counted-vmcnt pipeline)
  //    + aux prep (2816 blocks: Wo convert, cache_k, vT_old)
  qkv_gemm<<<3584, blk, 0, stream>>>(xb, wqkv, cosb, sinb, Wo, cache_k, cache_v,
                                     qb, keysb, valsT, wob);

  // 3) attention (R10 structure, XCD-locality block decode) -> bf16 (B,S,E)
  attn_mfma<<<B * H * (S / 64), blk, 0, stream>>>(qb, cosb, sinb, keysb, valsT, aout);

  // 4) output projection, counted-vmcnt pipeline, direct f32 stores
  oproj_gemm<<<512, blk, 0, stream>>>(aout, wob, out);
}